// Round 16
// baseline (104.105 us; speedup 1.0000x reference)
//
#include <hip/hip_runtime.h>
#include <hip/hip_bf16.h>
#include <math.h>

typedef __bf16 bf16;
typedef __bf16 bf16x4 __attribute__((ext_vector_type(4)));
typedef __bf16 bf16x8 __attribute__((ext_vector_type(8)));
typedef float f32x4 __attribute__((ext_vector_type(4)));
typedef unsigned short ushort8 __attribute__((ext_vector_type(8)));

#define MFMA16(a, b, c) __builtin_amdgcn_mfma_f32_16x16x32_bf16(a, b, c, 0, 0, 0)

__device__ inline bf16x8 frag2(bf16x4 a, bf16x4 b) {
    bf16x8 r;
    r[0] = a[0]; r[1] = a[1]; r[2] = a[2]; r[3] = a[3];
    r[4] = b[0]; r[5] = b[1]; r[6] = b[2]; r[7] = b[3];
    return r;
}

__device__ inline bf16x8 frag_from(const bf16* p0, const bf16* p1) {
    return frag2(*(const bf16x4*)p0, *(const bf16x4*)p1);
}

// async global->LDS, 16B per lane. LDS dest = wave-uniform base (+16B*lane).
__device__ inline void gld16(const bf16* g, bf16* l) {
    __builtin_amdgcn_global_load_lds(
        (const __attribute__((address_space(1))) void*)g,
        (__attribute__((address_space(3))) void*)l, 16, 0, 0);
}

// ---------------------------------------------------------------------------
// Kernel W: pack all six fp32 weights to bf16 (one-time, ~0.5 MB total).
// ---------------------------------------------------------------------------
__global__ __launch_bounds__(256) void k_wpack(
    const float* __restrict__ Wq, const float* __restrict__ Wk,
    const float* __restrict__ Wv, const float* __restrict__ Wo,
    const float* __restrict__ W1, const float* __restrict__ W2,
    bf16* __restrict__ Wqb, bf16* __restrict__ Wkb, bf16* __restrict__ Wvb,
    bf16* __restrict__ Wob, bf16* __restrict__ W1b, bf16* __restrict__ W2b)
{
    const unsigned u = blockIdx.x * 256 + threadIdx.x;   // 0..65535
    const float* src; bf16* dst; unsigned off;
    if      (u < 8192)  { src = Wq; dst = Wqb; off = u; }
    else if (u < 16384) { src = Wk; dst = Wkb; off = u - 8192; }
    else if (u < 24576) { src = Wv; dst = Wvb; off = u - 16384; }
    else if (u < 32768) { src = Wo; dst = Wob; off = u - 24576; }
    else if (u < 49152) { src = W1; dst = W1b; off = u - 32768; }
    else                { src = W2; dst = W2b; off = u - 49152; }
    f32x4 a = *(const f32x4*)(src + (size_t)off * 8);
    f32x4 b = *(const f32x4*)(src + (size_t)off * 8 + 4);
    bf16x8 v;
#pragma unroll
    for (int j = 0; j < 4; ++j) { v[j] = (bf16)a[j]; v[4 + j] = (bf16)b[j]; }
    *(bf16x8*)(dst + (size_t)off * 8) = v;
}

// ---------------------------------------------------------------------------
// Kernel 1: QKV projections, writing FRAGMENT-LINEAR outputs directly.
//   out[i][o] = sum_c in[c][i] * W[o][c] + b[o]   (Q scaled by 1/16)
// ---------------------------------------------------------------------------
__global__ __launch_bounds__(256) void k_qkv(
    const float* __restrict__ x, const float* __restrict__ y,
    const bf16* __restrict__ Wqb, const float* __restrict__ bq,
    const bf16* __restrict__ Wkb, const float* __restrict__ bk,
    const bf16* __restrict__ Wvb, const float* __restrict__ bv,
    bf16* __restrict__ Qf, bf16* __restrict__ Kf, bf16* __restrict__ Vf)
{
    const int zi = blockIdx.z;
    const float* src  = (zi == 0) ? x : y;
    const bf16* W     = (zi == 0) ? Wqb : (zi == 1 ? Wkb : Wvb);
    const float* bias = (zi == 0) ? bq : (zi == 1 ? bk : bv);
    bf16* dst         = (zi == 0) ? Qf : (zi == 1 ? Kf : Vf);
    const float scale = (zi == 0) ? 0.0625f : 1.0f;

    const int i0 = blockIdx.x * 64;
    const int o0 = blockIdx.y * 64;
    const int t = threadIdx.x;
    const int lane = t & 63;
    const int w = t >> 6;
    const int wr = w >> 1, wc = w & 1;
    const int l16 = lane & 15, lg = lane >> 4;

    __shared__ bf16 As[64][40];   // [m][k]
    __shared__ bf16 Bs[64][40];   // [n][k]
    __shared__ bf16 Tt[64][72];   // epilogue tile [row=pos][col=channel]

    f32x4 acc[2][2] = {};

    for (int kc = 0; kc < 256; kc += 32) {
        __syncthreads();
        for (int p = 0; p < 2; ++p) {
            int e = t + 256 * p;          // 0..511
            int c = e >> 4, m0 = (e & 15) * 4;
            f32x4 v = *(const f32x4*)&src[(kc + c) * 4096 + i0 + m0];
            for (int j = 0; j < 4; ++j) As[m0 + j][c] = (bf16)v[j];
        }
        {
            int n = t >> 2, c0 = (t & 3) * 8;
            *(ushort8*)&Bs[n][c0] =
                *(const ushort8*)(W + (size_t)(o0 + n) * 256 + kc + c0);
        }
        __syncthreads();
        const int c0 = 4 * lg;
        bf16x8 af[2], bfr[2];
        for (int mi = 0; mi < 2; ++mi) {
            int m = 32 * wr + 16 * mi + l16;
            af[mi] = frag_from(&As[m][c0], &As[m][c0 + 16]);
        }
        for (int ni = 0; ni < 2; ++ni) {
            int n = 32 * wc + 16 * ni + l16;
            bfr[ni] = frag_from(&Bs[n][c0], &Bs[n][c0 + 16]);
        }
        for (int mi = 0; mi < 2; ++mi)
            for (int ni = 0; ni < 2; ++ni)
                acc[mi][ni] = MFMA16(af[mi], bfr[ni], acc[mi][ni]);
    }

    for (int mi = 0; mi < 2; ++mi)
        for (int ni = 0; ni < 2; ++ni) {
            int n = 32 * wc + 16 * ni + l16;
            float bv_ = bias[o0 + n];
            for (int i = 0; i < 4; ++i)
                Tt[32 * wr + 16 * mi + 4 * lg + i][n] =
                    (bf16)((acc[mi][ni][i] + bv_) * scale);
        }
    __syncthreads();

    if (zi != 2) {
        // Q/K pack (frag-linear)
        for (int p = 0; p < 2; ++p) {
            int u = t + 256 * p;              // 0..511
            int Tl = u >> 8, cl = (u >> 7) & 1, kcl = (u >> 6) & 1, ln = u & 63;
            int l16_ = ln & 15, lg_ = ln >> 4;
            int r = 32 * Tl + 16 * cl + l16_;
            int c0 = 32 * kcl + 4 * lg_;
            bf16x8 v = frag_from(&Tt[r][c0], &Tt[r][c0 + 16]);
            size_t U = (size_t)(i0 / 32 + Tl) * 1024 + (size_t)cl * 512
                     + (size_t)(o0 / 32 + kcl) * 64 + ln;
            *(bf16x8*)(dst + U * 8) = v;
        }
    } else {
        // V pack (B-operand layout)
        for (int p = 0; p < 2; ++p) {
            int u = t + 256 * p;              // 0..511
            int Tl = u >> 8, nil = (u >> 6) & 3, ln = u & 63;
            int l16_ = ln & 15, lg_ = ln >> 4;
            bf16x8 v;
            for (int j = 0; j < 4; ++j) {
                v[j]     = Tt[32 * Tl + 4 * lg_ + j][16 * nil + l16_];
                v[4 + j] = Tt[32 * Tl + 16 + 4 * lg_ + j][16 * nil + l16_];
            }
            size_t U = (size_t)(i0 / 32 + Tl) * 1024
                     + (size_t)(o0 / 16 + nil) * 64 + ln;
            *(bf16x8*)(dst + U * 8) = v;
        }
    }
}

// ---------------------------------------------------------------------------
// Kernel 2: flash attention. qpw=32 (two Q frag sets share every K/V LDS
// read -> LDS traffic halved vs qpw=16), K AND V double-buffered (64KB),
// staging via global_load_lds (zero staging VGPRs -> ~120 VGPR + 128 AGPR
// = 2 waves/SIMD, 2 blocks/CU, 8 waves/CU). One barrier/tile; DMA for t+1
// issued at tile top has the whole tile to land. nsplit=16, grid (16,32).
// Swapped QK^T, in-register softmax, T13 defer-rescale.
// ---------------------------------------------------------------------------
__global__ __launch_bounds__(256) void k_flash(
    const bf16* __restrict__ Qf, const bf16* __restrict__ Kf,
    const bf16* __restrict__ Vf, bf16* __restrict__ Ot,
    float* __restrict__ statm, float* __restrict__ statl)
{
    __shared__ bf16 Ks[2][8192];    // 2 x 16KB K tiles (frag-linear)
    __shared__ bf16 Vs[2][8192];    // 2 x 16KB V tiles

    const int t = threadIdx.x;
    const int lane = t & 63;
    const int w = t >> 6;
    const int l16 = lane & 15, lg = lane >> 4;
    const int sp = blockIdx.x;                 // KV split 0..15 (XCD-affine)
    const int q0 = blockIdx.y * 128 + w * 32;  // wave's 32 q-rows
    const int T0 = sp * 8;
    const int NT = 8;

    // Q fragments, 2 q-subsets (coalesced frag-linear; pre-scaled by 1/16)
    bf16x8 Qfr[2][8];
#pragma unroll
    for (int qs = 0; qs < 2; ++qs) {
        int qq = q0 + 16 * qs;
        const bf16* qbp = Qf + ((size_t)(qq >> 5) * 1024 + (size_t)((qq >> 4) & 1) * 512) * 8;
#pragma unroll
        for (int kc = 0; kc < 8; ++kc)
            Qfr[qs][kc] = *(const bf16x8*)(qbp + (kc * 64 + lane) * 8);
    }

    float m_run[2] = {-1e30f, -1e30f}, l_run[2] = {0.f, 0.f};
    f32x4 O[2][16] = {};   // O[qs][ni][i] = O[q0+16qs+4lg+i][16ni+l16]

    // prologue: DMA tile T0 into buf 0
#pragma unroll
    for (int j = 0; j < 4; ++j) {
        gld16(Kf + ((size_t)T0 * 1024 + j * 256 + t) * 8,
              &Ks[0][(j * 256 + w * 64) * 8]);
        gld16(Vf + ((size_t)T0 * 1024 + j * 256 + t) * 8,
              &Vs[0][(j * 256 + w * 64) * 8]);
    }
    __syncthreads();

    for (int tt = 0; tt < NT; ++tt) {
        const int buf = tt & 1;
        if (tt < NT - 1) {           // DMA next tile into other buffers
            size_t Tn = (size_t)(T0 + tt + 1) * 1024;
#pragma unroll
            for (int j = 0; j < 4; ++j) {
                gld16(Kf + (Tn + j * 256 + t) * 8, &Ks[buf ^ 1][(j * 256 + w * 64) * 8]);
                gld16(Vf + (Tn + j * 256 + t) * 8, &Vs[buf ^ 1][(j * 256 + w * 64) * 8]);
            }
        }

        // ---- QK^T (swapped): S[qs][c]; key = 16c+4lg+i (in-tile), q = l16
        f32x4 S[2][2] = {};
        __builtin_amdgcn_s_setprio(1);
#pragma unroll
        for (int kc = 0; kc < 8; ++kc) {
            bf16x8 k0 = *(const bf16x8*)&Ks[buf][(kc * 64 + lane) * 8];
            bf16x8 k1 = *(const bf16x8*)&Ks[buf][(512 + kc * 64 + lane) * 8];
            S[0][0] = MFMA16(k0, Qfr[0][kc], S[0][0]);
            S[0][1] = MFMA16(k1, Qfr[0][kc], S[0][1]);
            S[1][0] = MFMA16(k0, Qfr[1][kc], S[1][0]);
            S[1][1] = MFMA16(k1, Qfr[1][kc], S[1][1]);
        }
        __builtin_amdgcn_s_setprio(0);

        // ---- in-register online softmax, defer-rescale (THR=8)
        float p[2][8];
        float mx[2];
#pragma unroll
        for (int qs = 0; qs < 2; ++qs) {
#pragma unroll
            for (int i = 0; i < 4; ++i) { p[qs][i] = S[qs][0][i]; p[qs][4 + i] = S[qs][1][i]; }
            float m_ = p[qs][0];
#pragma unroll
            for (int j = 1; j < 8; ++j) m_ = fmaxf(m_, p[qs][j]);
            m_ = fmaxf(m_, __shfl_xor(m_, 16));
            m_ = fmaxf(m_, __shfl_xor(m_, 32));
            mx[qs] = m_;
        }
        bool need = (mx[0] > m_run[0] + 8.f) || (mx[1] > m_run[1] + 8.f);
        if (__any(need)) {
            float corr[2];
#pragma unroll
            for (int qs = 0; qs < 2; ++qs) {
                float mn = fmaxf(m_run[qs], mx[qs]);
                corr[qs] = __expf(m_run[qs] - mn);
                m_run[qs] = mn;
                l_run[qs] *= corr[qs];
            }
            float cr[2][4];
#pragma unroll
            for (int qs = 0; qs < 2; ++qs)
#pragma unroll
                for (int i = 0; i < 4; ++i) cr[qs][i] = __shfl(corr[qs], 4 * lg + i);
#pragma unroll
            for (int qs = 0; qs < 2; ++qs)
#pragma unroll
                for (int ni = 0; ni < 16; ++ni)
#pragma unroll
                    for (int i = 0; i < 4; ++i) O[qs][ni][i] *= cr[qs][i];
        }

        bf16x8 pa[2];
#pragma unroll
        for (int qs = 0; qs < 2; ++qs) {
            float sum = 0.f;
#pragma unroll
            for (int j = 0; j < 8; ++j) {
                p[qs][j] = __expf(p[qs][j] - m_run[qs]);
                sum += p[qs][j];
            }
            sum += __shfl_xor(sum, 16);
            sum += __shfl_xor(sum, 32);
            l_run[qs] += sum;
#pragma unroll
            for (int j = 0; j < 8; ++j) pa[qs][j] = (bf16)p[qs][j];
        }

        // ---- PV: each V frag feeds both q-subsets
        __builtin_amdgcn_s_setprio(1);
#pragma unroll
        for (int ni = 0; ni < 16; ++ni) {
            bf16x8 vb = *(const bf16x8*)&Vs[buf][(ni * 64 + lane) * 8];
            O[0][ni] = MFMA16(pa[0], vb, O[0][ni]);
            O[1][ni] = MFMA16(pa[1], vb, O[1][ni]);
        }
        __builtin_amdgcn_s_setprio(0);

        __syncthreads();             // drains DMA; next tile ready
    }

    // ---- normalized partial output + stats
#pragma unroll
    for (int qs = 0; qs < 2; ++qs) {
        float il = 1.f / l_run[qs];          // valid for q=l16
        float li[4];
#pragma unroll
        for (int i = 0; i < 4; ++i) li[i] = __shfl(il, 4 * lg + i);
#pragma unroll
        for (int ni = 0; ni < 16; ++ni)
#pragma unroll
            for (int i = 0; i < 4; ++i) {
                int q = q0 + 16 * qs + 4 * lg + i;
                int d = 16 * ni + l16;
                Ot[((size_t)sp * 4096 + q) * 256 + d] = (bf16)(O[qs][ni][i] * li[i]);
            }
        if (lane < 16) {
            statm[sp * 4096 + q0 + 16 * qs + l16] = m_run[qs];
            statl[sp * 4096 + q0 + 16 * qs + l16] = l_run[qs];
        }
    }
}

// ---------------------------------------------------------------------------
// Kernel 3: merge nsplit splits inline, then z = att @ Wo^T + bo, channel LN.
// ---------------------------------------------------------------------------
__global__ __launch_bounds__(256) void k_proj_ln(
    const bf16* __restrict__ Ot, const float* __restrict__ statm,
    const float* __restrict__ statl, const bf16* __restrict__ Wob,
    const float* __restrict__ bo, const float* __restrict__ ln_w,
    const float* __restrict__ ln_b, bf16* __restrict__ zn, int nsplit)
{
    __shared__ bf16 As[32][264];     // merged attention rows (full 256 cols)
    __shared__ bf16 Bs[256][40];
    __shared__ float psum[4][32], psq[4][32];
    __shared__ float mean_l[32], inv_l[32];

    const int t = threadIdx.x, lane = t & 63, w = t >> 6;
    const int l16 = lane & 15, lg = lane >> 4;
    const int q0 = blockIdx.x * 32;

    // ---- merge splits: 2 passes; thread -> row rr*16+(t>>4), cols (t&15)*16
    for (int rr = 0; rr < 2; ++rr) {
        const int rloc = rr * 16 + (t >> 4);
        const int qg = q0 + rloc;
        const int d0 = (t & 15) * 16;
        float M = -1e30f;
        for (int s = 0; s < nsplit; ++s) M = fmaxf(M, statm[s * 4096 + qg]);
        float den = 0.f;
        float a[16] = {};
        for (int s = 0; s < nsplit; ++s) {
            float c = __expf(statm[s * 4096 + qg] - M) * statl[s * 4096 + qg];
            den += c;
            const bf16* pp = Ot + ((size_t)s * 4096 + qg) * 256 + d0;
            bf16x8 v0 = *(const bf16x8*)pp;
            bf16x8 v1 = *(const bf16x8*)(pp + 8);
#pragma unroll
            for (int j = 0; j < 8; ++j) { a[j] += c * (float)v0[j]; a[8 + j] += c * (float)v1[j]; }
        }
        float inv = 1.f / den;
        bf16x8 o0, o1;
#pragma unroll
        for (int j = 0; j < 8; ++j) { o0[j] = (bf16)(a[j] * inv); o1[j] = (bf16)(a[8 + j] * inv); }
        *(bf16x8*)&As[rloc][d0] = o0;
        *(bf16x8*)&As[rloc][d0 + 8] = o1;
    }

    f32x4 acc[2][4] = {};
    for (int kc = 0; kc < 256; kc += 32) {
        __syncthreads();
        for (int p = 0; p < 4; ++p) {
            int e = t + 256 * p;          // 0..1023
            int n = e >> 2, c0 = (e & 3) * 8;
            *(ushort8*)&Bs[n][c0] =
                *(const ushort8*)(Wob + (size_t)n * 256 + kc + c0);
        }
        __syncthreads();
        bf16x8 af[2];
        for (int mi = 0; mi < 2; ++mi)
            af[mi] = frag_from(&As[16 * mi + l16][kc + 4 * lg],
                               &As[16 * mi + l16][kc + 4 * lg + 16]);
        for (int ni = 0; ni < 4; ++ni) {
            int n = 64 * w + 16 * ni + l16;
            bf16x8 bfr = frag_from(&Bs[n][4 * lg], &Bs[n][4 * lg + 16]);
            acc[0][ni] = MFMA16(af[0], bfr, acc[0][ni]);
            acc[1][ni] = MFMA16(af[1], bfr, acc[1][ni]);
        }
    }

    float z[2][4][4];
    float rs[2][4] = {}, rq[2][4] = {};
    for (int ni = 0; ni < 4; ++ni) {
        int n = 64 * w + 16 * ni + l16;
        float b_ = bo[n];
        for (int mi = 0; mi < 2; ++mi)
            for (int i = 0; i < 4; ++i) {
                float v = acc[mi][ni][i] + b_;
                z[mi][ni][i] = v;
                rs[mi][i] += v;
                rq[mi][i] += v * v;
            }
    }
    for (int mi = 0; mi < 2; ++mi)
        for (int i = 0; i < 4; ++i) {
            float s = rs[mi][i], q = rq[mi][i];
            for (int msk = 1; msk <= 8; msk <<= 1) {
                s += __shfl_xor(s, msk);
                q += __shfl_xor(q, msk);
            }
            if (l16 == 0) {
                psum[w][16 * mi + 4 * lg + i] = s;
                psq[w][16 * mi + 4 * lg + i] = q;
            }
        }
    __syncthreads();
    if (t < 32) {
        float s = psum[0][t] + psum[1][t] + psum[2][t] + psum[3][t];
        float q = psq[0][t] + psq[1][t] + psq[2][t] + psq[3][t];
        float mean = s * (1.f / 256.f);
        float var = q * (1.f / 256.f) - mean * mean;
        mean_l[t] = mean;
        inv_l[t] = rsqrtf(var + 1e-6f);
    }
    __syncthreads();
    for (int ni = 0; ni < 4; ++ni) {
        int n = 64 * w + 16 * ni + l16;
        float g = ln_w[n], be = ln_b[n];
        for (int mi = 0; mi < 2; ++mi)
            for (int i = 0; i < 4; ++i) {
                int r = 16 * mi + 4 * lg + i;
                float v = (z[mi][ni][i] - mean_l[r]) * inv_l[r] * g + be;
                zn[(q0 + r) * 256 + n] = (bf16)v;
            }
    }
}

// ---------------------------------------------------------------------------
// Kernel 4: t1 = gelu(zn @ W1^T + b1); bf16 weights; LDS-transpose epilogue.
// ---------------------------------------------------------------------------
__global__ __launch_bounds__(256) void k_mlp1(
    const bf16* __restrict__ zn, const bf16* __restrict__ W1b,
    const float* __restrict__ b1, bf16* __restrict__ t1)
{
    __shared__ bf16 As[64][40];
    __shared__ bf16 Bs[64][40];
    __shared__ bf16 Tt[64][72];
    const int t = threadIdx.x, lane = t & 63, w = t >> 6;
    const int l16 = lane & 15, lg = lane >> 4;
    const int wr = w >> 1, wc = w & 1;
    const int i0 = blockIdx.x * 64, n0 = blockIdx.y * 64;
    f32x4 acc[2][2] = {};
    for (int kc = 0; kc < 256; kc += 32) {
        __syncthreads();
        {
            int r = t >> 2, u = t & 3;
            ushort8 v = *(const ushort8*)(zn + (i0 + r) * 256 + kc + 8 * u);
            *(ushort8*)((char*)&As[r][0] + 16 * u) = v;
        }
        {
            int n = t >> 2, c0 = (t & 3) * 8;
            *(ushort8*)&Bs[n][c0] =
                *(const ushort8*)(W1b + (size_t)(n0 + n) * 256 + kc + c0);
        }
        __syncthreads();
        bf16x8 af[2], bfr[2];
        for (int mi = 0; mi < 2; ++mi) {
            int m = 32 * wr + 16 * mi + l16;
            af[mi] = frag_from(&As[m][4 * lg], &As[m][4 * lg + 16]);
        }
        for (int ni = 0; ni < 2; ++ni) {
            int n = 32 * wc + 16 * ni + l16;
            bfr[ni] = frag_from(&Bs[n][4 * lg], &Bs[n][4 * lg + 16]);
        }
        for (int mi = 0; mi < 2; ++mi)
            for (int ni = 0; ni < 2; ++ni)
                acc[mi][ni] = MFMA16(af[mi], bfr[ni], acc[mi][ni]);
    }
    for (int ni = 0; ni < 2; ++ni) {
        int n = 32 * wc + 16 * ni + l16;
        float b_ = b1[n0 + n];
        for (int mi = 0; mi < 2; ++mi)
            for (int i = 0; i < 4; ++i) {
                float h = acc[mi][ni][i] + b_;
                float g = 0.5f * h * (1.f + erff(h * 0.70710678118f));
                Tt[32 * wr + 16 * mi + 4 * lg + i][n] = (bf16)g;
            }
    }
    __syncthreads();
    for (int p = 0; p < 2; ++p) {
        int e = t + 256 * p;
        int r = e >> 3, u = e & 7;
        *(bf16x8*)(t1 + (i0 + r) * 512 + n0 + 8 * u) = *(bf16x8*)&Tt[r][8 * u];
    }
}

// ---------------------------------------------------------------------------
// Kernel 5: t = t1 @ W2^T + b2 (bf16 W2); out[c][i] = x[c][i] + t[i][c]
// ---------------------------------------------------------------------------
__global__ __launch_bounds__(256) void k_mlp2(
    const bf16* __restrict__ t1, const bf16* __restrict__ W2b,
    const float* __restrict__ b2, const float* __restrict__ x,
    float* __restrict__ out)
{
    __shared__ bf16 As[64][40];
    __shared__ bf16 Bs[64][40];
    __shared__ float T[64][65];
    const int t = threadIdx.x, lane = t & 63, w = t >> 6;
    const int l16 = lane & 15, lg = lane >> 4;
    const int wr = w >> 1, wc = w & 1;
    const int i0 = blockIdx.x * 64, n0 = blockIdx.y * 64;
    f32x4 acc[2][2] = {};
    for (int kc = 0; kc < 512; kc += 32) {
        __syncthreads();
        {
            int r = t >> 2, u = t & 3;
            ushort8 v = *(const ushort8*)(t1 + (i0 + r) * 512 + kc + 8 * u);
            *(ushort8*)((char*)&As[r][0] + 16 * u) = v;
        }
        {
            int n = t >> 2, c0 = (t & 3) * 8;
            *(ushort8*)&Bs[n][c0] =
                *(const ushort8*)(W2b + (size_t)(n0 + n) * 512 + kc + c0);
        }
        __syncthreads();
        bf16x8 af[2], bfr[2];
        for (int mi = 0; mi < 2; ++mi) {
            int m = 32 * wr + 16 * mi + l16;
            af[mi] = frag_from(&As[m][4 * lg], &As[m][4 * lg + 16]);
        }
        for (int ni = 0; ni < 2; ++ni) {
            int n = 32 * wc + 16 * ni + l16;
            bfr[ni] = frag_from(&Bs[n][4 * lg], &Bs[n][4 * lg + 16]);
        }
        for (int mi = 0; mi < 2; ++mi)
            for (int ni = 0; ni < 2; ++ni)
                acc[mi][ni] = MFMA16(af[mi], bfr[ni], acc[mi][ni]);
    }
    for (int ni = 0; ni < 2; ++ni) {
        int nn = 32 * wc + 16 * ni + l16;
        float b_ = b2[n0 + nn];
        for (int mi = 0; mi < 2; ++mi)
            for (int i = 0; i < 4; ++i) {
                int mloc = 32 * wr + 16 * mi + 4 * lg + i;
                T[nn][mloc] = acc[mi][ni][i] + b_;
            }
    }
    __syncthreads();
    for (int p = 0; p < 4; ++p) {
        int e = t + 256 * p;              // 0..1023
        int nn = e >> 4, m4 = (e & 15) * 4;
        int c = n0 + nn, m = i0 + m4;
        f32x4 xv = *(const f32x4*)&x[c * 4096 + m];
        f32x4 o;
        for (int j = 0; j < 4; ++j) o[j] = xv[j] + T[nn][m4 + j];
        *(f32x4*)&out[c * 4096 + m] = o;
    }
}

// ---------------------------------------------------------------------------
extern "C" void kernel_launch(void* const* d_in, const int* in_sizes, int n_in,
                              void* d_out, int out_size, void* d_ws, size_t ws_size,
                              hipStream_t stream) {
    (void)in_sizes; (void)n_in; (void)out_size; (void)ws_size;
    const float* x   = (const float*)d_in[0];
    const float* y   = (const float*)d_in[1];
    const float* Wq  = (const float*)d_in[2];
    const float* bq  = (const float*)d_in[3];
    const float* Wk  = (const float*)d_in[4];
    const float* bk  = (const float*)d_in[5];
    const float* Wv  = (const float*)d_in[6];
    const float* bv  = (const float*)d_in[7];
    const float* Wo  = (const float*)d_in[8];
    const float* bo  = (const float*)d_in[9];
    const float* lnw = (const float*)d_in[10];
    const float* lnb = (const float*)d_in[11];
    const float* W1  = (const float*)d_in[12];
    const float* b1  = (const float*)d_in[13];
    const float* W2  = (const float*)d_in[14];
    const float* b2  = (const float*)d_in[15];
    float* out = (float*)d_out;

    char* ws = (char*)d_ws;
    const size_t MB = 1u << 20;
    const size_t KB = 1u << 10;
    // Layout (peak 39.5 MB):
    //  [0,2)      Qf    -> zn after flash
    //  [2,4)      Kf
    //  [4,6)      Vf
    //  [6,6.25)   statm (16 splits)   [6.25,6.5) statl
    //  [6.5,7.5)  packed bf16 weights
    //  [7.5,39.5) Ot (32MB, 16 splits); t1 reuses Ot post-proj_ln
    bf16*  Qf    = (bf16*)(ws + 0 * MB);
    bf16*  Kf    = (bf16*)(ws + 2 * MB);
    bf16*  Vf    = (bf16*)(ws + 4 * MB);
    float* statm = (float*)(ws + 6 * MB);
    float* statl = (float*)(ws + 6 * MB + 256 * KB);
    char*  wreg  = ws + 6 * MB + 512 * KB;
    bf16*  Wqb   = (bf16*)(wreg + 0 * KB);
    bf16*  Wkb   = (bf16*)(wreg + 128 * KB);
    bf16*  Wvb   = (bf16*)(wreg + 256 * KB);
    bf16*  Wob   = (bf16*)(wreg + 384 * KB);
    bf16*  W1b   = (bf16*)(wreg + 512 * KB);
    bf16*  W2b   = (bf16*)(wreg + 768 * KB);
    char*  big   = ws + 7 * MB + 512 * KB;
    bf16*  Ot    = (bf16*)big;
    bf16*  t1    = (bf16*)big;                 // post-proj_ln only (Ot dead)
    bf16*  zn    = (bf16*)(ws + 0 * MB);       // post-flash (Qf dead)

    k_wpack<<<dim3(256), 256, 0, stream>>>(Wq, Wk, Wv, Wo, W1, W2,
                                           Wqb, Wkb, Wvb, Wob, W1b, W2b);
    k_qkv<<<dim3(64, 4, 3), 256, 0, stream>>>(x, y, Wqb, bq, Wkb, bk, Wvb, bv,
                                              Qf, Kf, Vf);
    k_flash<<<dim3(16, 32), 256, 0, stream>>>(Qf, Kf, Vf, Ot, statm, statl);
    k_proj_ln<<<dim3(128), 256, 0, stream>>>(Ot, statm, statl, Wob, bo, lnw, lnb, zn, 16);
    k_mlp1<<<dim3(64, 8), 256, 0, stream>>>(zn, W1b, b1, t1);
    k_mlp2<<<dim3(64, 4), 256, 0, stream>>>(t1, W2b, b2, x, out);
}

// Round 17
// 82.717 us; speedup vs baseline: 1.2586x; 1.2586x over previous
//
#include <hip/hip_runtime.h>
#include <hip/hip_bf16.h>
#include <math.h>

typedef __bf16 bf16;
typedef __bf16 bf16x4 __attribute__((ext_vector_type(4)));
typedef __bf16 bf16x8 __attribute__((ext_vector_type(8)));
typedef float f32x4 __attribute__((ext_vector_type(4)));
typedef unsigned short ushort8 __attribute__((ext_vector_type(8)));

#define MFMA16(a, b, c) __builtin_amdgcn_mfma_f32_16x16x32_bf16(a, b, c, 0, 0, 0)

__device__ inline bf16x8 frag2(bf16x4 a, bf16x4 b) {
    bf16x8 r;
    r[0] = a[0]; r[1] = a[1]; r[2] = a[2]; r[3] = a[3];
    r[4] = b[0]; r[5] = b[1]; r[6] = b[2]; r[7] = b[3];
    return r;
}

__device__ inline bf16x8 frag_from(const bf16* p0, const bf16* p1) {
    return frag2(*(const bf16x4*)p0, *(const bf16x4*)p1);
}

// ---------------------------------------------------------------------------
// Kernel W: pack all six fp32 weights to bf16 (one-time, ~0.5 MB total).
// ---------------------------------------------------------------------------
__global__ __launch_bounds__(256) void k_wpack(
    const float* __restrict__ Wq, const float* __restrict__ Wk,
    const float* __restrict__ Wv, const float* __restrict__ Wo,
    const float* __restrict__ W1, const float* __restrict__ W2,
    bf16* __restrict__ Wqb, bf16* __restrict__ Wkb, bf16* __restrict__ Wvb,
    bf16* __restrict__ Wob, bf16* __restrict__ W1b, bf16* __restrict__ W2b)
{
    const unsigned u = blockIdx.x * 256 + threadIdx.x;   // 0..65535
    const float* src; bf16* dst; unsigned off;
    if      (u < 8192)  { src = Wq; dst = Wqb; off = u; }
    else if (u < 16384) { src = Wk; dst = Wkb; off = u - 8192; }
    else if (u < 24576) { src = Wv; dst = Wvb; off = u - 16384; }
    else if (u < 32768) { src = Wo; dst = Wob; off = u - 24576; }
    else if (u < 49152) { src = W1; dst = W1b; off = u - 32768; }
    else                { src = W2; dst = W2b; off = u - 49152; }
    f32x4 a = *(const f32x4*)(src + (size_t)off * 8);
    f32x4 b = *(const f32x4*)(src + (size_t)off * 8 + 4);
    bf16x8 v;
#pragma unroll
    for (int j = 0; j < 4; ++j) { v[j] = (bf16)a[j]; v[4 + j] = (bf16)b[j]; }
    *(bf16x8*)(dst + (size_t)off * 8) = v;
}

// ---------------------------------------------------------------------------
// Kernel 1: QKV projections, writing FRAGMENT-LINEAR outputs directly.
//   out[i][o] = sum_c in[c][i] * W[o][c] + b[o]   (Q scaled by 1/16)
// ---------------------------------------------------------------------------
__global__ __launch_bounds__(256) void k_qkv(
    const float* __restrict__ x, const float* __restrict__ y,
    const bf16* __restrict__ Wqb, const float* __restrict__ bq,
    const bf16* __restrict__ Wkb, const float* __restrict__ bk,
    const bf16* __restrict__ Wvb, const float* __restrict__ bv,
    bf16* __restrict__ Qf, bf16* __restrict__ Kf, bf16* __restrict__ Vf)
{
    const int zi = blockIdx.z;
    const float* src  = (zi == 0) ? x : y;
    const bf16* W     = (zi == 0) ? Wqb : (zi == 1 ? Wkb : Wvb);
    const float* bias = (zi == 0) ? bq : (zi == 1 ? bk : bv);
    bf16* dst         = (zi == 0) ? Qf : (zi == 1 ? Kf : Vf);
    const float scale = (zi == 0) ? 0.0625f : 1.0f;

    const int i0 = blockIdx.x * 64;
    const int o0 = blockIdx.y * 64;
    const int t = threadIdx.x;
    const int lane = t & 63;
    const int w = t >> 6;
    const int wr = w >> 1, wc = w & 1;
    const int l16 = lane & 15, lg = lane >> 4;

    __shared__ bf16 As[64][40];   // [m][k]
    __shared__ bf16 Bs[64][40];   // [n][k]
    __shared__ bf16 Tt[64][72];   // epilogue tile [row=pos][col=channel]

    f32x4 acc[2][2] = {};

    for (int kc = 0; kc < 256; kc += 32) {
        __syncthreads();
        for (int p = 0; p < 2; ++p) {
            int e = t + 256 * p;          // 0..511
            int c = e >> 4, m0 = (e & 15) * 4;
            f32x4 v = *(const f32x4*)&src[(kc + c) * 4096 + i0 + m0];
            for (int j = 0; j < 4; ++j) As[m0 + j][c] = (bf16)v[j];
        }
        {
            int n = t >> 2, c0 = (t & 3) * 8;
            *(ushort8*)&Bs[n][c0] =
                *(const ushort8*)(W + (size_t)(o0 + n) * 256 + kc + c0);
        }
        __syncthreads();
        const int c0 = 4 * lg;
        bf16x8 af[2], bfr[2];
        for (int mi = 0; mi < 2; ++mi) {
            int m = 32 * wr + 16 * mi + l16;
            af[mi] = frag_from(&As[m][c0], &As[m][c0 + 16]);
        }
        for (int ni = 0; ni < 2; ++ni) {
            int n = 32 * wc + 16 * ni + l16;
            bfr[ni] = frag_from(&Bs[n][c0], &Bs[n][c0 + 16]);
        }
        for (int mi = 0; mi < 2; ++mi)
            for (int ni = 0; ni < 2; ++ni)
                acc[mi][ni] = MFMA16(af[mi], bfr[ni], acc[mi][ni]);
    }

    for (int mi = 0; mi < 2; ++mi)
        for (int ni = 0; ni < 2; ++ni) {
            int n = 32 * wc + 16 * ni + l16;
            float bv_ = bias[o0 + n];
            for (int i = 0; i < 4; ++i)
                Tt[32 * wr + 16 * mi + 4 * lg + i][n] =
                    (bf16)((acc[mi][ni][i] + bv_) * scale);
        }
    __syncthreads();

    if (zi != 2) {
        // Q/K pack (frag-linear)
        for (int p = 0; p < 2; ++p) {
            int u = t + 256 * p;              // 0..511
            int Tl = u >> 8, cl = (u >> 7) & 1, kcl = (u >> 6) & 1, ln = u & 63;
            int l16_ = ln & 15, lg_ = ln >> 4;
            int r = 32 * Tl + 16 * cl + l16_;
            int c0 = 32 * kcl + 4 * lg_;
            bf16x8 v = frag_from(&Tt[r][c0], &Tt[r][c0 + 16]);
            size_t U = (size_t)(i0 / 32 + Tl) * 1024 + (size_t)cl * 512
                     + (size_t)(o0 / 32 + kcl) * 64 + ln;
            *(bf16x8*)(dst + U * 8) = v;
        }
    } else {
        // V pack (B-operand layout)
        for (int p = 0; p < 2; ++p) {
            int u = t + 256 * p;              // 0..511
            int Tl = u >> 8, nil = (u >> 6) & 3, ln = u & 63;
            int l16_ = ln & 15, lg_ = ln >> 4;
            bf16x8 v;
            for (int j = 0; j < 4; ++j) {
                v[j]     = Tt[32 * Tl + 4 * lg_ + j][16 * nil + l16_];
                v[4 + j] = Tt[32 * Tl + 16 + 4 * lg_ + j][16 * nil + l16_];
            }
            size_t U = (size_t)(i0 / 32 + Tl) * 1024
                     + (size_t)(o0 / 16 + nil) * 64 + ln;
            *(bf16x8*)(dst + U * 8) = v;
        }
    }
}

// ---------------------------------------------------------------------------
// Kernel 2: flash attention — R12 anchor (best measured): qpw=16, 4 waves x
// 16q = 64 q/block, 32-key tiles, double-buffered 64KB LDS (K and V),
// reg-staged issue-early/write-late, ONE barrier/tile, nsplit=8,
// grid (qb=64, split=8) = 512 blocks = 2 blocks/CU, 8 waves/CU.
// Swapped QK^T, in-register softmax, T13 defer-rescale. VGPR ~100-130.
// ---------------------------------------------------------------------------
__global__ __launch_bounds__(256) void k_flash(
    const bf16* __restrict__ Qf, const bf16* __restrict__ Kf,
    const bf16* __restrict__ Vf, bf16* __restrict__ Ot,
    float* __restrict__ statm, float* __restrict__ statl)
{
    __shared__ bf16 Ks[2][8192];    // 16KB per buf, frag-linear tile
    __shared__ bf16 Vs[2][8192];

    const int t = threadIdx.x;
    const int lane = t & 63;
    const int w = t >> 6;
    const int l16 = lane & 15, lg = lane >> 4;
    const int q0 = blockIdx.x * 64 + w * 16;   // wave's 16 q-rows
    const int split = blockIdx.y;              // 0..7
    const int T0 = split * 16;
    const int NT = 16;

    // Q fragments (coalesced frag-linear; pre-scaled by 1/16 in k_qkv)
    bf16x8 Qfr[8];
    {
        const bf16* qbp = Qf + ((size_t)(q0 >> 5) * 1024 + (size_t)((q0 >> 4) & 1) * 512) * 8;
#pragma unroll
        for (int kc = 0; kc < 8; ++kc)
            Qfr[kc] = *(const bf16x8*)(qbp + (kc * 64 + lane) * 8);
    }

    float m_run = -1e30f, l_run = 0.f;
    f32x4 O[16] = {};   // O[ni][i] = O[q0+4lg+i][16ni+l16]

    ushort8 kst[4], vst[4];
    // prologue: load + write tile T0 into buf 0
#pragma unroll
    for (int j = 0; j < 4; ++j) {
        kst[j] = *(const ushort8*)(Kf + ((size_t)T0 * 1024 + j * 256 + t) * 8);
        vst[j] = *(const ushort8*)(Vf + ((size_t)T0 * 1024 + j * 256 + t) * 8);
    }
#pragma unroll
    for (int j = 0; j < 4; ++j) {
        *(ushort8*)&Ks[0][(j * 256 + t) * 8] = kst[j];
        *(ushort8*)&Vs[0][(j * 256 + t) * 8] = vst[j];
    }
    __syncthreads();

    for (int tt = 0; tt < NT; ++tt) {
        const int buf = tt & 1;
        if (tt < NT - 1) {           // issue next tile's loads early
            int T = T0 + tt + 1;
#pragma unroll
            for (int j = 0; j < 4; ++j) {
                kst[j] = *(const ushort8*)(Kf + ((size_t)T * 1024 + j * 256 + t) * 8);
                vst[j] = *(const ushort8*)(Vf + ((size_t)T * 1024 + j * 256 + t) * 8);
            }
        }

        // ---- QK^T (swapped): key = 16c+4lg+i (in-tile), q = l16
        f32x4 S0 = {}, S1 = {};
        __builtin_amdgcn_s_setprio(1);
#pragma unroll
        for (int kc = 0; kc < 8; ++kc) {
            bf16x8 k0 = *(const bf16x8*)&Ks[buf][(kc * 64 + lane) * 8];
            bf16x8 k1 = *(const bf16x8*)&Ks[buf][(512 + kc * 64 + lane) * 8];
            S0 = MFMA16(k0, Qfr[kc], S0);
            S1 = MFMA16(k1, Qfr[kc], S1);
        }
        __builtin_amdgcn_s_setprio(0);

        // ---- in-register online softmax, defer-rescale (THR=8)
        float p[8];
#pragma unroll
        for (int i = 0; i < 4; ++i) { p[i] = S0[i]; p[4 + i] = S1[i]; }
        float mx = p[0];
#pragma unroll
        for (int j = 1; j < 8; ++j) mx = fmaxf(mx, p[j]);
        mx = fmaxf(mx, __shfl_xor(mx, 16));
        mx = fmaxf(mx, __shfl_xor(mx, 32));
        if (__any(mx > m_run + 8.f)) {
            float mn = fmaxf(m_run, mx);
            float corr = __expf(m_run - mn);
            m_run = mn;
            l_run *= corr;
            float cr[4];
#pragma unroll
            for (int i = 0; i < 4; ++i) cr[i] = __shfl(corr, 4 * lg + i);
#pragma unroll
            for (int ni = 0; ni < 16; ++ni)
#pragma unroll
                for (int i = 0; i < 4; ++i) O[ni][i] *= cr[i];
        }
        float sum = 0.f;
#pragma unroll
        for (int j = 0; j < 8; ++j) { p[j] = __expf(p[j] - m_run); sum += p[j]; }
        sum += __shfl_xor(sum, 16);
        sum += __shfl_xor(sum, 32);
        l_run += sum;
        bf16x8 pa;
#pragma unroll
        for (int j = 0; j < 8; ++j) pa[j] = (bf16)p[j];

        // ---- PV
        __builtin_amdgcn_s_setprio(1);
#pragma unroll
        for (int ni = 0; ni < 16; ++ni) {
            bf16x8 vb = *(const bf16x8*)&Vs[buf][(ni * 64 + lane) * 8];
            O[ni] = MFMA16(pa, vb, O[ni]);
        }
        __builtin_amdgcn_s_setprio(0);

        if (tt < NT - 1) {           // write-late into other buffer
#pragma unroll
            for (int j = 0; j < 4; ++j) {
                *(ushort8*)&Ks[buf ^ 1][(j * 256 + t) * 8] = kst[j];
                *(ushort8*)&Vs[buf ^ 1][(j * 256 + t) * 8] = vst[j];
            }
        }
        __syncthreads();
    }

    // ---- normalized partial output + stats
    float il = 1.f / l_run;          // valid for q=l16
    float li[4];
#pragma unroll
    for (int i = 0; i < 4; ++i) li[i] = __shfl(il, 4 * lg + i);
#pragma unroll
    for (int ni = 0; ni < 16; ++ni)
#pragma unroll
        for (int i = 0; i < 4; ++i) {
            int q = q0 + 4 * lg + i;
            int d = 16 * ni + l16;
            Ot[((size_t)split * 4096 + q) * 256 + d] = (bf16)(O[ni][i] * li[i]);
        }
    if (lane < 16) {
        statm[split * 4096 + q0 + l16] = m_run;
        statl[split * 4096 + q0 + l16] = l_run;
    }
}

// ---------------------------------------------------------------------------
// Kernel 3: merge 8 splits inline, then z = att @ Wo^T + bo, channel LN.
// BM=32 (grid 128); Wo pre-packed bf16.
// ---------------------------------------------------------------------------
__global__ __launch_bounds__(256) void k_proj_ln(
    const bf16* __restrict__ Ot, const float* __restrict__ statm,
    const float* __restrict__ statl, const bf16* __restrict__ Wob,
    const float* __restrict__ bo, const float* __restrict__ ln_w,
    const float* __restrict__ ln_b, bf16* __restrict__ zn)
{
    __shared__ bf16 As[32][264];     // merged attention rows (full 256 cols)
    __shared__ bf16 Bs[256][40];
    __shared__ float psum[4][32], psq[4][32];
    __shared__ float mean_l[32], inv_l[32];

    const int t = threadIdx.x, lane = t & 63, w = t >> 6;
    const int l16 = lane & 15, lg = lane >> 4;
    const int q0 = blockIdx.x * 32;
    const int nsplit = 8;

    // ---- merge splits: 2 passes; thread -> row rr*16+(t>>4), cols (t&15)*16
    for (int rr = 0; rr < 2; ++rr) {
        const int rloc = rr * 16 + (t >> 4);
        const int qg = q0 + rloc;
        const int d0 = (t & 15) * 16;
        float M = -1e30f;
        for (int s = 0; s < nsplit; ++s) M = fmaxf(M, statm[s * 4096 + qg]);
        float den = 0.f;
        float a[16] = {};
        for (int s = 0; s < nsplit; ++s) {
            float c = __expf(statm[s * 4096 + qg] - M) * statl[s * 4096 + qg];
            den += c;
            const bf16* pp = Ot + ((size_t)s * 4096 + qg) * 256 + d0;
            bf16x8 v0 = *(const bf16x8*)pp;
            bf16x8 v1 = *(const bf16x8*)(pp + 8);
#pragma unroll
            for (int j = 0; j < 8; ++j) { a[j] += c * (float)v0[j]; a[8 + j] += c * (float)v1[j]; }
        }
        float inv = 1.f / den;
        bf16x8 o0, o1;
#pragma unroll
        for (int j = 0; j < 8; ++j) { o0[j] = (bf16)(a[j] * inv); o1[j] = (bf16)(a[8 + j] * inv); }
        *(bf16x8*)&As[rloc][d0] = o0;
        *(bf16x8*)&As[rloc][d0 + 8] = o1;
    }

    f32x4 acc[2][4] = {};
    for (int kc = 0; kc < 256; kc += 32) {
        __syncthreads();
        for (int p = 0; p < 4; ++p) {
            int e = t + 256 * p;          // 0..1023
            int n = e >> 2, c0 = (e & 3) * 8;
            *(ushort8*)&Bs[n][c0] =
                *(const ushort8*)(Wob + (size_t)n * 256 + kc + c0);
        }
        __syncthreads();
        bf16x8 af[2];
        for (int mi = 0; mi < 2; ++mi)
            af[mi] = frag_from(&As[16 * mi + l16][kc + 4 * lg],
                               &As[16 * mi + l16][kc + 4 * lg + 16]);
        for (int ni = 0; ni < 4; ++ni) {
            int n = 64 * w + 16 * ni + l16;
            bf16x8 bfr = frag_from(&Bs[n][4 * lg], &Bs[n][4 * lg + 16]);
            acc[0][ni] = MFMA16(af[0], bfr, acc[0][ni]);
            acc[1][ni] = MFMA16(af[1], bfr, acc[1][ni]);
        }
    }

    float z[2][4][4];
    float rs[2][4] = {}, rq[2][4] = {};
    for (int ni = 0; ni < 4; ++ni) {
        int n = 64 * w + 16 * ni + l16;
        float b_ = bo[n];
        for (int mi = 0; mi < 2; ++mi)
            for (int i = 0; i < 4; ++i) {
                float v = acc[mi][ni][i] + b_;
                z[mi][ni][i] = v;
                rs[mi][i] += v;
                rq[mi][i] += v * v;
            }
    }
    for (int mi = 0; mi < 2; ++mi)
        for (int i = 0; i < 4; ++i) {
            float s = rs[mi][i], q = rq[mi][i];
            for (int msk = 1; msk <= 8; msk <<= 1) {
                s += __shfl_xor(s, msk);
                q += __shfl_xor(q, msk);
            }
            if (l16 == 0) {
                psum[w][16 * mi + 4 * lg + i] = s;
                psq[w][16 * mi + 4 * lg + i] = q;
            }
        }
    __syncthreads();
    if (t < 32) {
        float s = psum[0][t] + psum[1][t] + psum[2][t] + psum[3][t];
        float q = psq[0][t] + psq[1][t] + psq[2][t] + psq[3][t];
        float mean = s * (1.f / 256.f);
        float var = q * (1.f / 256.f) - mean * mean;
        mean_l[t] = mean;
        inv_l[t] = rsqrtf(var + 1e-6f);
    }
    __syncthreads();
    for (int ni = 0; ni < 4; ++ni) {
        int n = 64 * w + 16 * ni + l16;
        float g = ln_w[n], be = ln_b[n];
        for (int mi = 0; mi < 2; ++mi)
            for (int i = 0; i < 4; ++i) {
                int r = 16 * mi + 4 * lg + i;
                float v = (z[mi][ni][i] - mean_l[r]) * inv_l[r] * g + be;
                zn[(q0 + r) * 256 + n] = (bf16)v;
            }
    }
}

// ---------------------------------------------------------------------------
// Kernel 4: t1 = gelu(zn @ W1^T + b1); bf16 weights; LDS-transpose epilogue.
// ---------------------------------------------------------------------------
__global__ __launch_bounds__(256) void k_mlp1(
    const bf16* __restrict__ zn, const bf16* __restrict__ W1b,
    const float* __restrict__ b1, bf16* __restrict__ t1)
{
    __shared__ bf16 As[64][40];
    __shared__ bf16 Bs[64][40];
    __shared__ bf16 Tt[64][72];
    const int t = threadIdx.x, lane = t & 63, w = t >> 6;
    const int l16 = lane & 15, lg = lane >> 4;
    const int wr = w >> 1, wc = w & 1;
    const int i0 = blockIdx.x * 64, n0 = blockIdx.y * 64;
    f32x4 acc[2][2] = {};
    for (int kc = 0; kc < 256; kc += 32) {
        __syncthreads();
        {
            int r = t >> 2, u = t & 3;
            ushort8 v = *(const ushort8*)(zn + (i0 + r) * 256 + kc + 8 * u);
            *(ushort8*)((char*)&As[r][0] + 16 * u) = v;
        }
        {
            int n = t >> 2, c0 = (t & 3) * 8;
            *(ushort8*)&Bs[n][c0] =
                *(const ushort8*)(W1b + (size_t)(n0 + n) * 256 + kc + c0);
        }
        __syncthreads();
        bf16x8 af[2], bfr[2];
        for (int mi = 0; mi < 2; ++mi) {
            int m = 32 * wr + 16 * mi + l16;
            af[mi] = frag_from(&As[m][4 * lg], &As[m][4 * lg + 16]);
        }
        for (int ni = 0; ni < 2; ++ni) {
            int n = 32 * wc + 16 * ni + l16;
            bfr[ni] = frag_from(&Bs[n][4 * lg], &Bs[n][4 * lg + 16]);
        }
        for (int mi = 0; mi < 2; ++mi)
            for (int ni = 0; ni < 2; ++ni)
                acc[mi][ni] = MFMA16(af[mi], bfr[ni], acc[mi][ni]);
    }
    for (int ni = 0; ni < 2; ++ni) {
        int n = 32 * wc + 16 * ni + l16;
        float b_ = b1[n0 + n];
        for (int mi = 0; mi < 2; ++mi)
            for (int i = 0; i < 4; ++i) {
                float h = acc[mi][ni][i] + b_;
                float g = 0.5f * h * (1.f + erff(h * 0.70710678118f));
                Tt[32 * wr + 16 * mi + 4 * lg + i][n] = (bf16)g;
            }
    }
    __syncthreads();
    for (int p = 0; p < 2; ++p) {
        int e = t + 256 * p;
        int r = e >> 3, u = e & 7;
        *(bf16x8*)(t1 + (i0 + r) * 512 + n0 + 8 * u) = *(bf16x8*)&Tt[r][8 * u];
    }
}

// ---------------------------------------------------------------------------
// Kernel 5: t = t1 @ W2^T + b2 (bf16 W2); out[c][i] = x[c][i] + t[i][c]
// ---------------------------------------------------------------------------
__global__ __launch_bounds__(256) void k_mlp2(
    const bf16* __restrict__ t1, const bf16* __restrict__ W2b,
    const float* __restrict__ b2, const float* __restrict__ x,
    float* __restrict__ out)
{
    __shared__ bf16 As[64][40];
    __shared__ bf16 Bs[64][40];
    __shared__ float T[64][65];
    const int t = threadIdx.x, lane = t & 63, w = t >> 6;
    const int l16 = lane & 15, lg = lane >> 4;
    const int wr = w >> 1, wc = w & 1;
    const int i0 = blockIdx.x * 64, n0 = blockIdx.y * 64;
    f32x4 acc[2][2] = {};
    for (int kc = 0; kc < 512; kc += 32) {
        __syncthreads();
        {
            int r = t >> 2, u = t & 3;
            ushort8 v = *(const ushort8*)(t1 + (i0 + r) * 512 + kc + 8 * u);
            *(ushort8*)((char*)&As[r][0] + 16 * u) = v;
        }
        {
            int n = t >> 2, c0 = (t & 3) * 8;
            *(ushort8*)&Bs[n][c0] =
                *(const ushort8*)(W2b + (size_t)(n0 + n) * 512 + kc + c0);
        }
        __syncthreads();
        bf16x8 af[2], bfr[2];
        for (int mi = 0; mi < 2; ++mi) {
            int m = 32 * wr + 16 * mi + l16;
            af[mi] = frag_from(&As[m][4 * lg], &As[m][4 * lg + 16]);
        }
        for (int ni = 0; ni < 2; ++ni) {
            int n = 32 * wc + 16 * ni + l16;
            bfr[ni] = frag_from(&Bs[n][4 * lg], &Bs[n][4 * lg + 16]);
        }
        for (int mi = 0; mi < 2; ++mi)
            for (int ni = 0; ni < 2; ++ni)
                acc[mi][ni] = MFMA16(af[mi], bfr[ni], acc[mi][ni]);
    }
    for (int ni = 0; ni < 2; ++ni) {
        int nn = 32 * wc + 16 * ni + l16;
        float b_ = b2[n0 + nn];
        for (int mi = 0; mi < 2; ++mi)
            for (int i = 0; i < 4; ++i) {
                int mloc = 32 * wr + 16 * mi + 4 * lg + i;
                T[nn][mloc] = acc[mi][ni][i] + b_;
            }
    }
    __syncthreads();
    for (int p = 0; p < 4; ++p) {
        int e = t + 256 * p;              // 0..1023
        int nn = e >> 4, m4 = (e & 15) * 4;
        int c = n0 + nn, m = i0 + m4;
        f32x4 xv = *(const f32x4*)&x[c * 4096 + m];
        f32x4 o;
        for (int j = 0; j < 4; ++j) o[j] = xv[j] + T[nn][m4 + j];
        *(f32x4*)&out[c * 4096 + m] = o;
    }
}

// ---------------------------------------------------------------------------
extern "C" void kernel_launch(void* const* d_in, const int* in_sizes, int n_in,
                              void* d_out, int out_size, void* d_ws, size_t ws_size,
                              hipStream_t stream) {
    (void)in_sizes; (void)n_in; (void)out_size; (void)ws_size;
    const float* x   = (const float*)d_in[0];
    const float* y   = (const float*)d_in[1];
    const float* Wq  = (const float*)d_in[2];
    const float* bq  = (const float*)d_in[3];
    const float* Wk  = (const float*)d_in[4];
    const float* bk  = (const float*)d_in[5];
    const float* Wv  = (const float*)d_in[6];
    const float* bv  = (const float*)d_in[7];
    const float* Wo  = (const float*)d_in[8];
    const float* bo  = (const float*)d_in[9];
    const float* lnw = (const float*)d_in[10];
    const float* lnb = (const float*)d_in[11];
    const float* W1  = (const float*)d_in[12];
    const float* b1  = (const float*)d_in[13];
    const float* W2  = (const float*)d_in[14];
    const float* b2  = (const float*)d_in[15];
    float* out = (float*)d_out;

    char* ws = (char*)d_ws;
    const size_t MB = 1u << 20;
    const size_t KB = 1u << 10;
    // Layout (peak 23.5 MB):
    //  [0,2)      Qf    -> zn after flash
    //  [2,4)      Kf
    //  [4,6)      Vf
    //  [6,6.25)   statm (8 splits)   [6.25,6.5) statl
    //  [6.5,7.5)  packed bf16 weights (Wqb,Wkb,Wvb,Wob 128K; W1b,W2b 256K)
    //  [7.5,23.5) Ot (16MB); t1 reuses Ot post-proj_ln
    bf16*  Qf    = (bf16*)(ws + 0 * MB);
    bf16*  Kf    = (bf16*)(ws + 2 * MB);
    bf16*  Vf    = (bf16*)(ws + 4 * MB);
    float* statm = (float*)(ws + 6 * MB);
    float* statl = (float*)(ws + 6 * MB + 256 * KB);
    char*  wreg  = ws + 6 * MB + 512 * KB;
    bf16*  Wqb   = (bf16*)(wreg + 0 * KB);
    bf16*  Wkb   = (bf16*)(wreg + 128 * KB);
    bf16*  Wvb   = (bf16*)(wreg + 256 * KB);
    bf16*  Wob   = (bf16*)(wreg + 384 * KB);
    bf16*  W1b   = (bf16*)(wreg + 512 * KB);
    bf16*  W2b   = (bf16*)(wreg + 768 * KB);
    char*  big   = ws + 7 * MB + 512 * KB;
    bf16*  Ot    = (bf16*)big;
    bf16*  t1    = (bf16*)big;                 // post-proj_ln only (Ot dead)
    bf16*  zn    = (bf16*)(ws + 0 * MB);       // post-flash (Qf dead)

    k_wpack<<<dim3(256), 256, 0, stream>>>(Wq, Wk, Wv, Wo, W1, W2,
                                           Wqb, Wkb, Wvb, Wob, W1b, W2b);
    k_qkv<<<dim3(64, 4, 3), 256, 0, stream>>>(x, y, Wqb, bq, Wkb, bk, Wvb, bv,
                                              Qf, Kf, Vf);
    k_flash<<<dim3(64, 8), 256, 0, stream>>>(Qf, Kf, Vf, Ot, statm, statl);
    k_proj_ln<<<dim3(128), 256, 0, stream>>>(Ot, statm, statl, Wob, bo, lnw, lnb, zn);
    k_mlp1<<<dim3(64, 8), 256, 0, stream>>>(zn, W1b, b1, t1);
    k_mlp2<<<dim3(64, 4), 256, 0, stream>>>(t1, W2b, b2, x, out);
}

// Round 18
// 82.551 us; speedup vs baseline: 1.2611x; 1.0020x over previous
//
#include <hip/hip_runtime.h>
#include <hip/hip_bf16.h>
#include <math.h>

typedef __bf16 bf16;
typedef __bf16 bf16x4 __attribute__((ext_vector_type(4)));
typedef __bf16 bf16x8 __attribute__((ext_vector_type(8)));
typedef float f32x4 __attribute__((ext_vector_type(4)));
typedef unsigned short ushort8 __attribute__((ext_vector_type(8)));

#define MFMA16(a, b, c) __builtin_amdgcn_mfma_f32_16x16x32_bf16(a, b, c, 0, 0, 0)

__device__ inline bf16x8 frag2(bf16x4 a, bf16x4 b) {
    bf16x8 r;
    r[0] = a[0]; r[1] = a[1]; r[2] = a[2]; r[3] = a[3];
    r[4] = b[0]; r[5] = b[1]; r[6] = b[2]; r[7] = b[3];
    return r;
}

__device__ inline bf16x8 frag_from(const bf16* p0, const bf16* p1) {
    return frag2(*(const bf16x4*)p0, *(const bf16x4*)p1);
}

// ---------------------------------------------------------------------------
// Kernel W: pack all six fp32 weights to bf16 (one-time, ~0.5 MB total).
// ---------------------------------------------------------------------------
__global__ __launch_bounds__(256) void k_wpack(
    const float* __restrict__ Wq, const float* __restrict__ Wk,
    const float* __restrict__ Wv, const float* __restrict__ Wo,
    const float* __restrict__ W1, const float* __restrict__ W2,
    bf16* __restrict__ Wqb, bf16* __restrict__ Wkb, bf16* __restrict__ Wvb,
    bf16* __restrict__ Wob, bf16* __restrict__ W1b, bf16* __restrict__ W2b)
{
    const unsigned u = blockIdx.x * 256 + threadIdx.x;   // 0..65535
    const float* src; bf16* dst; unsigned off;
    if      (u < 8192)  { src = Wq; dst = Wqb; off = u; }
    else if (u < 16384) { src = Wk; dst = Wkb; off = u - 8192; }
    else if (u < 24576) { src = Wv; dst = Wvb; off = u - 16384; }
    else if (u < 32768) { src = Wo; dst = Wob; off = u - 24576; }
    else if (u < 49152) { src = W1; dst = W1b; off = u - 32768; }
    else                { src = W2; dst = W2b; off = u - 49152; }
    f32x4 a = *(const f32x4*)(src + (size_t)off * 8);
    f32x4 b = *(const f32x4*)(src + (size_t)off * 8 + 4);
    bf16x8 v;
#pragma unroll
    for (int j = 0; j < 4; ++j) { v[j] = (bf16)a[j]; v[4 + j] = (bf16)b[j]; }
    *(bf16x8*)(dst + (size_t)off * 8) = v;
}

// ---------------------------------------------------------------------------
// Kernel 1: QKV projections, writing FRAGMENT-LINEAR outputs directly.
//   out[i][o] = sum_c in[c][i] * W[o][c] + b[o]   (Q scaled by 1/16)
// ---------------------------------------------------------------------------
__global__ __launch_bounds__(256) void k_qkv(
    const float* __restrict__ x, const float* __restrict__ y,
    const bf16* __restrict__ Wqb, const float* __restrict__ bq,
    const bf16* __restrict__ Wkb, const float* __restrict__ bk,
    const bf16* __restrict__ Wvb, const float* __restrict__ bv,
    bf16* __restrict__ Qf, bf16* __restrict__ Kf, bf16* __restrict__ Vf)
{
    const int zi = blockIdx.z;
    const float* src  = (zi == 0) ? x : y;
    const bf16* W     = (zi == 0) ? Wqb : (zi == 1 ? Wkb : Wvb);
    const float* bias = (zi == 0) ? bq : (zi == 1 ? bk : bv);
    bf16* dst         = (zi == 0) ? Qf : (zi == 1 ? Kf : Vf);
    const float scale = (zi == 0) ? 0.0625f : 1.0f;

    const int i0 = blockIdx.x * 64;
    const int o0 = blockIdx.y * 64;
    const int t = threadIdx.x;
    const int lane = t & 63;
    const int w = t >> 6;
    const int wr = w >> 1, wc = w & 1;
    const int l16 = lane & 15, lg = lane >> 4;

    __shared__ bf16 As[64][40];   // [m][k]
    __shared__ bf16 Bs[64][40];   // [n][k]
    __shared__ bf16 Tt[64][72];   // epilogue tile [row=pos][col=channel]

    f32x4 acc[2][2] = {};

    for (int kc = 0; kc < 256; kc += 32) {
        __syncthreads();
        for (int p = 0; p < 2; ++p) {
            int e = t + 256 * p;          // 0..511
            int c = e >> 4, m0 = (e & 15) * 4;
            f32x4 v = *(const f32x4*)&src[(kc + c) * 4096 + i0 + m0];
            for (int j = 0; j < 4; ++j) As[m0 + j][c] = (bf16)v[j];
        }
        {
            int n = t >> 2, c0 = (t & 3) * 8;
            *(ushort8*)&Bs[n][c0] =
                *(const ushort8*)(W + (size_t)(o0 + n) * 256 + kc + c0);
        }
        __syncthreads();
        const int c0 = 4 * lg;
        bf16x8 af[2], bfr[2];
        for (int mi = 0; mi < 2; ++mi) {
            int m = 32 * wr + 16 * mi + l16;
            af[mi] = frag_from(&As[m][c0], &As[m][c0 + 16]);
        }
        for (int ni = 0; ni < 2; ++ni) {
            int n = 32 * wc + 16 * ni + l16;
            bfr[ni] = frag_from(&Bs[n][c0], &Bs[n][c0 + 16]);
        }
        for (int mi = 0; mi < 2; ++mi)
            for (int ni = 0; ni < 2; ++ni)
                acc[mi][ni] = MFMA16(af[mi], bfr[ni], acc[mi][ni]);
    }

    for (int mi = 0; mi < 2; ++mi)
        for (int ni = 0; ni < 2; ++ni) {
            int n = 32 * wc + 16 * ni + l16;
            float bv_ = bias[o0 + n];
            for (int i = 0; i < 4; ++i)
                Tt[32 * wr + 16 * mi + 4 * lg + i][n] =
                    (bf16)((acc[mi][ni][i] + bv_) * scale);
        }
    __syncthreads();

    if (zi != 2) {
        // Q/K pack (frag-linear)
        for (int p = 0; p < 2; ++p) {
            int u = t + 256 * p;              // 0..511
            int Tl = u >> 8, cl = (u >> 7) & 1, kcl = (u >> 6) & 1, ln = u & 63;
            int l16_ = ln & 15, lg_ = ln >> 4;
            int r = 32 * Tl + 16 * cl + l16_;
            int c0 = 32 * kcl + 4 * lg_;
            bf16x8 v = frag_from(&Tt[r][c0], &Tt[r][c0 + 16]);
            size_t U = (size_t)(i0 / 32 + Tl) * 1024 + (size_t)cl * 512
                     + (size_t)(o0 / 32 + kcl) * 64 + ln;
            *(bf16x8*)(dst + U * 8) = v;
        }
    } else {
        // V pack (B-operand layout)
        for (int p = 0; p < 2; ++p) {
            int u = t + 256 * p;              // 0..511
            int Tl = u >> 8, nil = (u >> 6) & 3, ln = u & 63;
            int l16_ = ln & 15, lg_ = ln >> 4;
            bf16x8 v;
            for (int j = 0; j < 4; ++j) {
                v[j]     = Tt[32 * Tl + 4 * lg_ + j][16 * nil + l16_];
                v[4 + j] = Tt[32 * Tl + 16 + 4 * lg_ + j][16 * nil + l16_];
            }
            size_t U = (size_t)(i0 / 32 + Tl) * 1024
                     + (size_t)(o0 / 16 + nil) * 64 + ln;
            *(bf16x8*)(dst + U * 8) = v;
        }
    }
}

// ---------------------------------------------------------------------------
// Kernel 2: flash attention — R12 anchor (best measured): qpw=16, 4 waves x
// 16q = 64 q/block, 32-key tiles, double-buffered 64KB LDS (K and V),
// reg-staged issue-early/write-late, ONE barrier/tile, nsplit=8,
// grid (qb=64, split=8) = 512 blocks = 2 blocks/CU, 8 waves/CU.
// Swapped QK^T, in-register softmax, T13 defer-rescale. VGPR ~100-130.
// ---------------------------------------------------------------------------
__global__ __launch_bounds__(256) void k_flash(
    const bf16* __restrict__ Qf, const bf16* __restrict__ Kf,
    const bf16* __restrict__ Vf, bf16* __restrict__ Ot,
    float* __restrict__ statm, float* __restrict__ statl)
{
    __shared__ bf16 Ks[2][8192];    // 16KB per buf, frag-linear tile
    __shared__ bf16 Vs[2][8192];

    const int t = threadIdx.x;
    const int lane = t & 63;
    const int w = t >> 6;
    const int l16 = lane & 15, lg = lane >> 4;
    const int q0 = blockIdx.x * 64 + w * 16;   // wave's 16 q-rows
    const int split = blockIdx.y;              // 0..7
    const int T0 = split * 16;
    const int NT = 16;

    // Q fragments (coalesced frag-linear; pre-scaled by 1/16 in k_qkv)
    bf16x8 Qfr[8];
    {
        const bf16* qbp = Qf + ((size_t)(q0 >> 5) * 1024 + (size_t)((q0 >> 4) & 1) * 512) * 8;
#pragma unroll
        for (int kc = 0; kc < 8; ++kc)
            Qfr[kc] = *(const bf16x8*)(qbp + (kc * 64 + lane) * 8);
    }

    float m_run = -1e30f, l_run = 0.f;
    f32x4 O[16] = {};   // O[ni][i] = O[q0+4lg+i][16ni+l16]

    ushort8 kst[4], vst[4];
    // prologue: load + write tile T0 into buf 0
#pragma unroll
    for (int j = 0; j < 4; ++j) {
        kst[j] = *(const ushort8*)(Kf + ((size_t)T0 * 1024 + j * 256 + t) * 8);
        vst[j] = *(const ushort8*)(Vf + ((size_t)T0 * 1024 + j * 256 + t) * 8);
    }
#pragma unroll
    for (int j = 0; j < 4; ++j) {
        *(ushort8*)&Ks[0][(j * 256 + t) * 8] = kst[j];
        *(ushort8*)&Vs[0][(j * 256 + t) * 8] = vst[j];
    }
    __syncthreads();

    for (int tt = 0; tt < NT; ++tt) {
        const int buf = tt & 1;
        if (tt < NT - 1) {           // issue next tile's loads early
            int T = T0 + tt + 1;
#pragma unroll
            for (int j = 0; j < 4; ++j) {
                kst[j] = *(const ushort8*)(Kf + ((size_t)T * 1024 + j * 256 + t) * 8);
                vst[j] = *(const ushort8*)(Vf + ((size_t)T * 1024 + j * 256 + t) * 8);
            }
        }

        // ---- QK^T (swapped): key = 16c+4lg+i (in-tile), q = l16
        f32x4 S0 = {}, S1 = {};
        __builtin_amdgcn_s_setprio(1);
#pragma unroll
        for (int kc = 0; kc < 8; ++kc) {
            bf16x8 k0 = *(const bf16x8*)&Ks[buf][(kc * 64 + lane) * 8];
            bf16x8 k1 = *(const bf16x8*)&Ks[buf][(512 + kc * 64 + lane) * 8];
            S0 = MFMA16(k0, Qfr[kc], S0);
            S1 = MFMA16(k1, Qfr[kc], S1);
        }
        __builtin_amdgcn_s_setprio(0);

        // ---- in-register online softmax, defer-rescale (THR=8)
        float p[8];
#pragma unroll
        for (int i = 0; i < 4; ++i) { p[i] = S0[i]; p[4 + i] = S1[i]; }
        float mx = p[0];
#pragma unroll
        for (int j = 1; j < 8; ++j) mx = fmaxf(mx, p[j]);
        mx = fmaxf(mx, __shfl_xor(mx, 16));
        mx = fmaxf(mx, __shfl_xor(mx, 32));
        if (__any(mx > m_run + 8.f)) {
            float mn = fmaxf(m_run, mx);
            float corr = __expf(m_run - mn);
            m_run = mn;
            l_run *= corr;
            float cr[4];
#pragma unroll
            for (int i = 0; i < 4; ++i) cr[i] = __shfl(corr, 4 * lg + i);
#pragma unroll
            for (int ni = 0; ni < 16; ++ni)
#pragma unroll
                for (int i = 0; i < 4; ++i) O[ni][i] *= cr[i];
        }
        float sum = 0.f;
#pragma unroll
        for (int j = 0; j < 8; ++j) { p[j] = __expf(p[j] - m_run); sum += p[j]; }
        sum += __shfl_xor(sum, 16);
        sum += __shfl_xor(sum, 32);
        l_run += sum;
        bf16x8 pa;
#pragma unroll
        for (int j = 0; j < 8; ++j) pa[j] = (bf16)p[j];

        // ---- PV
        __builtin_amdgcn_s_setprio(1);
#pragma unroll
        for (int ni = 0; ni < 16; ++ni) {
            bf16x8 vb = *(const bf16x8*)&Vs[buf][(ni * 64 + lane) * 8];
            O[ni] = MFMA16(pa, vb, O[ni]);
        }
        __builtin_amdgcn_s_setprio(0);

        if (tt < NT - 1) {           // write-late into other buffer
#pragma unroll
            for (int j = 0; j < 4; ++j) {
                *(ushort8*)&Ks[buf ^ 1][(j * 256 + t) * 8] = kst[j];
                *(ushort8*)&Vs[buf ^ 1][(j * 256 + t) * 8] = vst[j];
            }
        }
        __syncthreads();
    }

    // ---- normalized partial output + stats
    float il = 1.f / l_run;          // valid for q=l16
    float li[4];
#pragma unroll
    for (int i = 0; i < 4; ++i) li[i] = __shfl(il, 4 * lg + i);
#pragma unroll
    for (int ni = 0; ni < 16; ++ni)
#pragma unroll
        for (int i = 0; i < 4; ++i) {
            int q = q0 + 4 * lg + i;
            int d = 16 * ni + l16;
            Ot[((size_t)split * 4096 + q) * 256 + d] = (bf16)(O[ni][i] * li[i]);
        }
    if (lane < 16) {
        statm[split * 4096 + q0 + l16] = m_run;
        statl[split * 4096 + q0 + l16] = l_run;
    }
}

// ---------------------------------------------------------------------------
// Kernel 3: merge 8 splits inline, then z = att @ Wo^T + bo, channel LN.
// BM=32 (grid 128); Wo pre-packed bf16.
// ---------------------------------------------------------------------------
__global__ __launch_bounds__(256) void k_proj_ln(
    const bf16* __restrict__ Ot, const float* __restrict__ statm,
    const float* __restrict__ statl, const bf16* __restrict__ Wob,
    const float* __restrict__ bo, const float* __restrict__ ln_w,
    const float* __restrict__ ln_b, bf16* __restrict__ zn)
{
    __shared__ bf16 As[32][264];     // merged attention rows (full 256 cols)
    __shared__ bf16 Bs[256][40];
    __shared__ float psum[4][32], psq[4][32];
    __shared__ float mean_l[32], inv_l[32];

    const int t = threadIdx.x, lane = t & 63, w = t >> 6;
    const int l16 = lane & 15, lg = lane >> 4;
    const int q0 = blockIdx.x * 32;
    const int nsplit = 8;

    // ---- merge splits: 2 passes; thread -> row rr*16+(t>>4), cols (t&15)*16
    for (int rr = 0; rr < 2; ++rr) {
        const int rloc = rr * 16 + (t >> 4);
        const int qg = q0 + rloc;
        const int d0 = (t & 15) * 16;
        float M = -1e30f;
        for (int s = 0; s < nsplit; ++s) M = fmaxf(M, statm[s * 4096 + qg]);
        float den = 0.f;
        float a[16] = {};
        for (int s = 0; s < nsplit; ++s) {
            float c = __expf(statm[s * 4096 + qg] - M) * statl[s * 4096 + qg];
            den += c;
            const bf16* pp = Ot + ((size_t)s * 4096 + qg) * 256 + d0;
            bf16x8 v0 = *(const bf16x8*)pp;
            bf16x8 v1 = *(const bf16x8*)(pp + 8);
#pragma unroll
            for (int j = 0; j < 8; ++j) { a[j] += c * (float)v0[j]; a[8 + j] += c * (float)v1[j]; }
        }
        float inv = 1.f / den;
        bf16x8 o0, o1;
#pragma unroll
        for (int j = 0; j < 8; ++j) { o0[j] = (bf16)(a[j] * inv); o1[j] = (bf16)(a[8 + j] * inv); }
        *(bf16x8*)&As[rloc][d0] = o0;
        *(bf16x8*)&As[rloc][d0 + 8] = o1;
    }

    f32x4 acc[2][4] = {};
    for (int kc = 0; kc < 256; kc += 32) {
        __syncthreads();
        for (int p = 0; p < 4; ++p) {
            int e = t + 256 * p;          // 0..1023
            int n = e >> 2, c0 = (e & 3) * 8;
            *(ushort8*)&Bs[n][c0] =
                *(const ushort8*)(Wob + (size_t)n * 256 + kc + c0);
        }
        __syncthreads();
        bf16x8 af[2];
        for (int mi = 0; mi < 2; ++mi)
            af[mi] = frag_from(&As[16 * mi + l16][kc + 4 * lg],
                               &As[16 * mi + l16][kc + 4 * lg + 16]);
        for (int ni = 0; ni < 4; ++ni) {
            int n = 64 * w + 16 * ni + l16;
            bf16x8 bfr = frag_from(&Bs[n][4 * lg], &Bs[n][4 * lg + 16]);
            acc[0][ni] = MFMA16(af[0], bfr, acc[0][ni]);
            acc[1][ni] = MFMA16(af[1], bfr, acc[1][ni]);
        }
    }

    float z[2][4][4];
    float rs[2][4] = {}, rq[2][4] = {};
    for (int ni = 0; ni < 4; ++ni) {
        int n = 64 * w + 16 * ni + l16;
        float b_ = bo[n];
        for (int mi = 0; mi < 2; ++mi)
            for (int i = 0; i < 4; ++i) {
                float v = acc[mi][ni][i] + b_;
                z[mi][ni][i] = v;
                rs[mi][i] += v;
                rq[mi][i] += v * v;
            }
    }
    for (int mi = 0; mi < 2; ++mi)
        for (int i = 0; i < 4; ++i) {
            float s = rs[mi][i], q = rq[mi][i];
            for (int msk = 1; msk <= 8; msk <<= 1) {
                s += __shfl_xor(s, msk);
                q += __shfl_xor(q, msk);
            }
            if (l16 == 0) {
                psum[w][16 * mi + 4 * lg + i] = s;
                psq[w][16 * mi + 4 * lg + i] = q;
            }
        }
    __syncthreads();
    if (t < 32) {
        float s = psum[0][t] + psum[1][t] + psum[2][t] + psum[3][t];
        float q = psq[0][t] + psq[1][t] + psq[2][t] + psq[3][t];
        float mean = s * (1.f / 256.f);
        float var = q * (1.f / 256.f) - mean * mean;
        mean_l[t] = mean;
        inv_l[t] = rsqrtf(var + 1e-6f);
    }
    __syncthreads();
    for (int ni = 0; ni < 4; ++ni) {
        int n = 64 * w + 16 * ni + l16;
        float g = ln_w[n], be = ln_b[n];
        for (int mi = 0; mi < 2; ++mi)
            for (int i = 0; i < 4; ++i) {
                int r = 16 * mi + 4 * lg + i;
                float v = (z[mi][ni][i] - mean_l[r]) * inv_l[r] * g + be;
                zn[(q0 + r) * 256 + n] = (bf16)v;
            }
    }
}

// ---------------------------------------------------------------------------
// Kernel 4: t1 = gelu(zn @ W1^T + b1); bf16 weights; LDS-transpose epilogue.
// ---------------------------------------------------------------------------
__global__ __launch_bounds__(256) void k_mlp1(
    const bf16* __restrict__ zn, const bf16* __restrict__ W1b,
    const float* __restrict__ b1, bf16* __restrict__ t1)
{
    __shared__ bf16 As[64][40];
    __shared__ bf16 Bs[64][40];
    __shared__ bf16 Tt[64][72];
    const int t = threadIdx.x, lane = t & 63, w = t >> 6;
    const int l16 = lane & 15, lg = lane >> 4;
    const int wr = w >> 1, wc = w & 1;
    const int i0 = blockIdx.x * 64, n0 = blockIdx.y * 64;
    f32x4 acc[2][2] = {};
    for (int kc = 0; kc < 256; kc += 32) {
        __syncthreads();
        {
            int r = t >> 2, u = t & 3;
            ushort8 v = *(const ushort8*)(zn + (i0 + r) * 256 + kc + 8 * u);
            *(ushort8*)((char*)&As[r][0] + 16 * u) = v;
        }
        {
            int n = t >> 2, c0 = (t & 3) * 8;
            *(ushort8*)&Bs[n][c0] =
                *(const ushort8*)(W1b + (size_t)(n0 + n) * 256 + kc + c0);
        }
        __syncthreads();
        bf16x8 af[2], bfr[2];
        for (int mi = 0; mi < 2; ++mi) {
            int m = 32 * wr + 16 * mi + l16;
            af[mi] = frag_from(&As[m][4 * lg], &As[m][4 * lg + 16]);
        }
        for (int ni = 0; ni < 2; ++ni) {
            int n = 32 * wc + 16 * ni + l16;
            bfr[ni] = frag_from(&Bs[n][4 * lg], &Bs[n][4 * lg + 16]);
        }
        for (int mi = 0; mi < 2; ++mi)
            for (int ni = 0; ni < 2; ++ni)
                acc[mi][ni] = MFMA16(af[mi], bfr[ni], acc[mi][ni]);
    }
    for (int ni = 0; ni < 2; ++ni) {
        int n = 32 * wc + 16 * ni + l16;
        float b_ = b1[n0 + n];
        for (int mi = 0; mi < 2; ++mi)
            for (int i = 0; i < 4; ++i) {
                float h = acc[mi][ni][i] + b_;
                float g = 0.5f * h * (1.f + erff(h * 0.70710678118f));
                Tt[32 * wr + 16 * mi + 4 * lg + i][n] = (bf16)g;
            }
    }
    __syncthreads();
    for (int p = 0; p < 2; ++p) {
        int e = t + 256 * p;
        int r = e >> 3, u = e & 7;
        *(bf16x8*)(t1 + (i0 + r) * 512 + n0 + 8 * u) = *(bf16x8*)&Tt[r][8 * u];
    }
}

// ---------------------------------------------------------------------------
// Kernel 5: t = t1 @ W2^T + b2 (bf16 W2); out[c][i] = x[c][i] + t[i][c]
// ---------------------------------------------------------------------------
__global__ __launch_bounds__(256) void k_mlp2(
    const bf16* __restrict__ t1, const bf16* __restrict__ W2b,
    const float* __restrict__ b2, const float* __restrict__ x,
    float* __restrict__ out)
{
    __shared__ bf16 As[64][40];
    __shared__ bf16 Bs[64][40];
    __shared__ float T[64][65];
    const int t = threadIdx.x, lane = t & 63, w = t >> 6;
    const int l16 = lane & 15, lg = lane >> 4;
    const int wr = w >> 1, wc = w & 1;
    const int i0 = blockIdx.x * 64, n0 = blockIdx.y * 64;
    f32x4 acc[2][2] = {};
    for (int kc = 0; kc < 512; kc += 32) {
        __syncthreads();
        {
            int r = t >> 2, u = t & 3;
            ushort8 v = *(const ushort8*)(t1 + (i0 + r) * 512 + kc + 8 * u);
            *(ushort8*)((char*)&As[r][0] + 16 * u) = v;
        }
        {
            int n = t >> 2, c0 = (t & 3) * 8;
            *(ushort8*)&Bs[n][c0] =
                *(const ushort8*)(W2b + (size_t)(n0 + n) * 512 + kc + c0);
        }
        __syncthreads();
        bf16x8 af[2], bfr[2];
        for (int mi = 0; mi < 2; ++mi) {
            int m = 32 * wr + 16 * mi + l16;
            af[mi] = frag_from(&As[m][4 * lg], &As[m][4 * lg + 16]);
        }
        for (int ni = 0; ni < 2; ++ni) {
            int n = 32 * wc + 16 * ni + l16;
            bfr[ni] = frag_from(&Bs[n][4 * lg], &Bs[n][4 * lg + 16]);
        }
        for (int mi = 0; mi < 2; ++mi)
            for (int ni = 0; ni < 2; ++ni)
                acc[mi][ni] = MFMA16(af[mi], bfr[ni], acc[mi][ni]);
    }
    for (int ni = 0; ni < 2; ++ni) {
        int nn = 32 * wc + 16 * ni + l16;
        float b_ = b2[n0 + nn];
        for (int mi = 0; mi < 2; ++mi)
            for (int i = 0; i < 4; ++i) {
                int mloc = 32 * wr + 16 * mi + 4 * lg + i;
                T[nn][mloc] = acc[mi][ni][i] + b_;
            }
    }
    __syncthreads();
    for (int p = 0; p < 4; ++p) {
        int e = t + 256 * p;              // 0..1023
        int nn = e >> 4, m4 = (e & 15) * 4;
        int c = n0 + nn, m = i0 + m4;
        f32x4 xv = *(const f32x4*)&x[c * 4096 + m];
        f32x4 o;
        for (int j = 0; j < 4; ++j) o[j] = xv[j] + T[nn][m4 + j];
        *(f32x4*)&out[c * 4096 + m] = o;
    }
}

// ---------------------------------------------------------------------------
extern "C" void kernel_launch(void* const* d_in, const int* in_sizes, int n_in,
                              void* d_out, int out_size, void* d_ws, size_t ws_size,
                              hipStream_t stream) {
    (void)in_sizes; (void)n_in; (void)out_size; (void)ws_size;
    const float* x   = (const float*)d_in[0];
    const float* y   = (const float*)d_in[1];
    const float* Wq  = (const float*)d_in[2];
    const float* bq  = (const float*)d_in[3];
    const float* Wk  = (const float*)d_in[4];
    const float* bk  = (const float*)d_in[5];
    const float* Wv  = (const float*)d_in[6];
    const float* bv  = (const float*)d_in[7];
    const float* Wo  = (const float*)d_in[8];
    const float* bo  = (const float*)d_in[9];
    const float* lnw = (const float*)d_in[10];
    const float* lnb = (const float*)d_in[11];
    const float* W1  = (const float*)d_in[12];
    const float* b1  = (const float*)d_in[13];
    const float* W2  = (const float*)d_in[14];
    const float* b2  = (const float*)d_in[15];
    float* out = (float*)d_out;

    char* ws = (char*)d_ws;
    const size_t MB = 1u << 20;
    const size_t KB = 1u << 10;
    // Layout (peak 23.5 MB):
    //  [0,2)      Qf    -> zn after flash
    //  [2,4)      Kf
    //  [4,6)      Vf
    //  [6,6.25)   statm (8 splits)   [6.25,6.5) statl
    //  [6.5,7.5)  packed bf16 weights (Wqb,Wkb,Wvb,Wob 128K; W1b,W2b 256K)
    //  [7.5,23.5) Ot (16MB); t1 reuses Ot post-proj_ln
    bf16*  Qf    = (bf16*)(ws + 0 * MB);
    bf16*  Kf    = (bf16*)(ws + 2 * MB);
    bf16*  Vf    = (bf16*)(ws + 4 * MB);
    float* statm = (float*)(ws + 6 * MB);
    float* statl = (float*)(ws + 6 * MB + 256 * KB);
    char*  wreg  = ws + 6 * MB + 512 * KB;
    bf16*  Wqb   = (bf16*)(wreg + 0 * KB);
    bf16*  Wkb   = (bf16*)(wreg + 128 * KB);
    bf16*  Wvb   = (bf16*)(wreg + 256 * KB);
    bf16*  Wob   = (bf16*)(wreg + 384 * KB);
    bf16*  W1b   = (bf16*)(wreg + 512 * KB);
    bf16*  W2b   = (bf16*)(wreg + 768 * KB);
    char*  big   = ws + 7 * MB + 512 * KB;
    bf16*  Ot    = (bf16*)big;
    bf16*  t1    = (bf16*)big;                 // post-proj_ln only (Ot dead)
    bf16*  zn    = (bf16*)(ws + 0 * MB);       // post-flash (Qf dead)

    k_wpack<<<dim3(256), 256, 0, stream>>>(Wq, Wk, Wv, Wo, W1, W2,
                                           Wqb, Wkb, Wvb, Wob, W1b, W2b);
    k_qkv<<<dim3(64, 4, 3), 256, 0, stream>>>(x, y, Wqb, bq, Wkb, bk, Wvb, bv,
                                              Qf, Kf, Vf);
    k_flash<<<dim3(64, 8), 256, 0, stream>>>(Qf, Kf, Vf, Ot, statm, statl);
    k_proj_ln<<<dim3(128), 256, 0, stream>>>(Ot, statm, statl, Wob, bo, lnw, lnb, zn);
    k_mlp1<<<dim3(64, 8), 256, 0, stream>>>(zn, W1b, b1, t1);
    k_mlp2<<<dim3(64, 4), 256, 0, stream>>>(t1, W2b, b2, x, out);
}

// Round 19
// 78.501 us; speedup vs baseline: 1.3262x; 1.0516x over previous
//
#include <hip/hip_runtime.h>
#include <hip/hip_bf16.h>
#include <math.h>

typedef __bf16 bf16;
typedef __bf16 bf16x4 __attribute__((ext_vector_type(4)));
typedef __bf16 bf16x8 __attribute__((ext_vector_type(8)));
typedef float f32x4 __attribute__((ext_vector_type(4)));
typedef unsigned short ushort8 __attribute__((ext_vector_type(8)));

#define MFMA16(a, b, c) __builtin_amdgcn_mfma_f32_16x16x32_bf16(a, b, c, 0, 0, 0)

__device__ inline bf16x8 frag2(bf16x4 a, bf16x4 b) {
    bf16x8 r;
    r[0] = a[0]; r[1] = a[1]; r[2] = a[2]; r[3] = a[3];
    r[4] = b[0]; r[5] = b[1]; r[6] = b[2]; r[7] = b[3];
    return r;
}

__device__ inline bf16x8 frag_from(const bf16* p0, const bf16* p1) {
    return frag2(*(const bf16x4*)p0, *(const bf16x4*)p1);
}

// ---------------------------------------------------------------------------
// Kernel W: pack all six fp32 weights to bf16 (one-time, ~0.5 MB total).
// ---------------------------------------------------------------------------
__global__ __launch_bounds__(256) void k_wpack(
    const float* __restrict__ Wq, const float* __restrict__ Wk,
    const float* __restrict__ Wv, const float* __restrict__ Wo,
    const float* __restrict__ W1, const float* __restrict__ W2,
    bf16* __restrict__ Wqb, bf16* __restrict__ Wkb, bf16* __restrict__ Wvb,
    bf16* __restrict__ Wob, bf16* __restrict__ W1b, bf16* __restrict__ W2b)
{
    const unsigned u = blockIdx.x * 256 + threadIdx.x;   // 0..65535
    const float* src; bf16* dst; unsigned off;
    if      (u < 8192)  { src = Wq; dst = Wqb; off = u; }
    else if (u < 16384) { src = Wk; dst = Wkb; off = u - 8192; }
    else if (u < 24576) { src = Wv; dst = Wvb; off = u - 16384; }
    else if (u < 32768) { src = Wo; dst = Wob; off = u - 24576; }
    else if (u < 49152) { src = W1; dst = W1b; off = u - 32768; }
    else                { src = W2; dst = W2b; off = u - 49152; }
    f32x4 a = *(const f32x4*)(src + (size_t)off * 8);
    f32x4 b = *(const f32x4*)(src + (size_t)off * 8 + 4);
    bf16x8 v;
#pragma unroll
    for (int j = 0; j < 4; ++j) { v[j] = (bf16)a[j]; v[4 + j] = (bf16)b[j]; }
    *(bf16x8*)(dst + (size_t)off * 8) = v;
}

// ---------------------------------------------------------------------------
// Kernel 1: QKV projections, frag-linear outputs. K-phases of 128:
// 4 barriers total (was 16).
// ---------------------------------------------------------------------------
__global__ __launch_bounds__(256) void k_qkv(
    const float* __restrict__ x, const float* __restrict__ y,
    const bf16* __restrict__ Wqb, const float* __restrict__ bq,
    const bf16* __restrict__ Wkb, const float* __restrict__ bk,
    const bf16* __restrict__ Wvb, const float* __restrict__ bv,
    bf16* __restrict__ Qf, bf16* __restrict__ Kf, bf16* __restrict__ Vf)
{
    const int zi = blockIdx.z;
    const float* src  = (zi == 0) ? x : y;
    const bf16* W     = (zi == 0) ? Wqb : (zi == 1 ? Wkb : Wvb);
    const float* bias = (zi == 0) ? bq : (zi == 1 ? bk : bv);
    bf16* dst         = (zi == 0) ? Qf : (zi == 1 ? Kf : Vf);
    const float scale = (zi == 0) ? 0.0625f : 1.0f;

    const int i0 = blockIdx.x * 64;
    const int o0 = blockIdx.y * 64;
    const int t = threadIdx.x;
    const int lane = t & 63;
    const int w = t >> 6;
    const int wr = w >> 1, wc = w & 1;
    const int l16 = lane & 15, lg = lane >> 4;

    __shared__ bf16 As[64][136];  // [m][k-phase 128]
    __shared__ bf16 Bs[64][136];  // [n][k-phase 128]
    __shared__ bf16 Tt[64][72];   // epilogue tile [row=pos][col=channel]

    f32x4 acc[2][2] = {};

    for (int ph = 0; ph < 2; ++ph) {
        const int kc0 = ph * 128;
        __syncthreads();
        for (int p = 0; p < 8; ++p) {
            int e = t + 256 * p;          // 0..2047
            int c = e >> 4, m0 = (e & 15) * 4;
            f32x4 v = *(const f32x4*)&src[(kc0 + c) * 4096 + i0 + m0];
            for (int j = 0; j < 4; ++j) As[m0 + j][c] = (bf16)v[j];
        }
        for (int p = 0; p < 4; ++p) {
            int e = t + 256 * p;          // 0..1023
            int n = e >> 4, c0 = (e & 15) * 8;
            *(ushort8*)&Bs[n][c0] =
                *(const ushort8*)(W + (size_t)(o0 + n) * 256 + kc0 + c0);
        }
        __syncthreads();
#pragma unroll
        for (int kc = 0; kc < 4; ++kc) {
            const int c0 = 32 * kc + 4 * lg;
            bf16x8 af[2], bfr[2];
            for (int mi = 0; mi < 2; ++mi) {
                int m = 32 * wr + 16 * mi + l16;
                af[mi] = frag_from(&As[m][c0], &As[m][c0 + 16]);
            }
            for (int ni = 0; ni < 2; ++ni) {
                int n = 32 * wc + 16 * ni + l16;
                bfr[ni] = frag_from(&Bs[n][c0], &Bs[n][c0 + 16]);
            }
            for (int mi = 0; mi < 2; ++mi)
                for (int ni = 0; ni < 2; ++ni)
                    acc[mi][ni] = MFMA16(af[mi], bfr[ni], acc[mi][ni]);
        }
    }

    for (int mi = 0; mi < 2; ++mi)
        for (int ni = 0; ni < 2; ++ni) {
            int n = 32 * wc + 16 * ni + l16;
            float bv_ = bias[o0 + n];
            for (int i = 0; i < 4; ++i)
                Tt[32 * wr + 16 * mi + 4 * lg + i][n] =
                    (bf16)((acc[mi][ni][i] + bv_) * scale);
        }
    __syncthreads();

    if (zi != 2) {
        // Q/K pack (frag-linear)
        for (int p = 0; p < 2; ++p) {
            int u = t + 256 * p;              // 0..511
            int Tl = u >> 8, cl = (u >> 7) & 1, kcl = (u >> 6) & 1, ln = u & 63;
            int l16_ = ln & 15, lg_ = ln >> 4;
            int r = 32 * Tl + 16 * cl + l16_;
            int c0 = 32 * kcl + 4 * lg_;
            bf16x8 v = frag_from(&Tt[r][c0], &Tt[r][c0 + 16]);
            size_t U = (size_t)(i0 / 32 + Tl) * 1024 + (size_t)cl * 512
                     + (size_t)(o0 / 32 + kcl) * 64 + ln;
            *(bf16x8*)(dst + U * 8) = v;
        }
    } else {
        // V pack (B-operand layout)
        for (int p = 0; p < 2; ++p) {
            int u = t + 256 * p;              // 0..511
            int Tl = u >> 8, nil = (u >> 6) & 3, ln = u & 63;
            int l16_ = ln & 15, lg_ = ln >> 4;
            bf16x8 v;
            for (int j = 0; j < 4; ++j) {
                v[j]     = Tt[32 * Tl + 4 * lg_ + j][16 * nil + l16_];
                v[4 + j] = Tt[32 * Tl + 16 + 4 * lg_ + j][16 * nil + l16_];
            }
            size_t U = (size_t)(i0 / 32 + Tl) * 1024
                     + (size_t)(o0 / 16 + nil) * 64 + ln;
            *(bf16x8*)(dst + U * 8) = v;
        }
    }
}

// ---------------------------------------------------------------------------
// Kernel 2: flash attention — R12 anchor (best measured). UNCHANGED.
// ---------------------------------------------------------------------------
__global__ __launch_bounds__(256) void k_flash(
    const bf16* __restrict__ Qf, const bf16* __restrict__ Kf,
    const bf16* __restrict__ Vf, bf16* __restrict__ Ot,
    float* __restrict__ statm, float* __restrict__ statl)
{
    __shared__ bf16 Ks[2][8192];    // 16KB per buf, frag-linear tile
    __shared__ bf16 Vs[2][8192];

    const int t = threadIdx.x;
    const int lane = t & 63;
    const int w = t >> 6;
    const int l16 = lane & 15, lg = lane >> 4;
    const int q0 = blockIdx.x * 64 + w * 16;   // wave's 16 q-rows
    const int split = blockIdx.y;              // 0..7
    const int T0 = split * 16;
    const int NT = 16;

    bf16x8 Qfr[8];
    {
        const bf16* qbp = Qf + ((size_t)(q0 >> 5) * 1024 + (size_t)((q0 >> 4) & 1) * 512) * 8;
#pragma unroll
        for (int kc = 0; kc < 8; ++kc)
            Qfr[kc] = *(const bf16x8*)(qbp + (kc * 64 + lane) * 8);
    }

    float m_run = -1e30f, l_run = 0.f;
    f32x4 O[16] = {};   // O[ni][i] = O[q0+4lg+i][16ni+l16]

    ushort8 kst[4], vst[4];
#pragma unroll
    for (int j = 0; j < 4; ++j) {
        kst[j] = *(const ushort8*)(Kf + ((size_t)T0 * 1024 + j * 256 + t) * 8);
        vst[j] = *(const ushort8*)(Vf + ((size_t)T0 * 1024 + j * 256 + t) * 8);
    }
#pragma unroll
    for (int j = 0; j < 4; ++j) {
        *(ushort8*)&Ks[0][(j * 256 + t) * 8] = kst[j];
        *(ushort8*)&Vs[0][(j * 256 + t) * 8] = vst[j];
    }
    __syncthreads();

    for (int tt = 0; tt < NT; ++tt) {
        const int buf = tt & 1;
        if (tt < NT - 1) {           // issue next tile's loads early
            int T = T0 + tt + 1;
#pragma unroll
            for (int j = 0; j < 4; ++j) {
                kst[j] = *(const ushort8*)(Kf + ((size_t)T * 1024 + j * 256 + t) * 8);
                vst[j] = *(const ushort8*)(Vf + ((size_t)T * 1024 + j * 256 + t) * 8);
            }
        }

        // ---- QK^T (swapped): key = 16c+4lg+i (in-tile), q = l16
        f32x4 S0 = {}, S1 = {};
        __builtin_amdgcn_s_setprio(1);
#pragma unroll
        for (int kc = 0; kc < 8; ++kc) {
            bf16x8 k0 = *(const bf16x8*)&Ks[buf][(kc * 64 + lane) * 8];
            bf16x8 k1 = *(const bf16x8*)&Ks[buf][(512 + kc * 64 + lane) * 8];
            S0 = MFMA16(k0, Qfr[kc], S0);
            S1 = MFMA16(k1, Qfr[kc], S1);
        }
        __builtin_amdgcn_s_setprio(0);

        // ---- in-register online softmax, defer-rescale (THR=8)
        float p[8];
#pragma unroll
        for (int i = 0; i < 4; ++i) { p[i] = S0[i]; p[4 + i] = S1[i]; }
        float mx = p[0];
#pragma unroll
        for (int j = 1; j < 8; ++j) mx = fmaxf(mx, p[j]);
        mx = fmaxf(mx, __shfl_xor(mx, 16));
        mx = fmaxf(mx, __shfl_xor(mx, 32));
        if (__any(mx > m_run + 8.f)) {
            float mn = fmaxf(m_run, mx);
            float corr = __expf(m_run - mn);
            m_run = mn;
            l_run *= corr;
            float cr[4];
#pragma unroll
            for (int i = 0; i < 4; ++i) cr[i] = __shfl(corr, 4 * lg + i);
#pragma unroll
            for (int ni = 0; ni < 16; ++ni)
#pragma unroll
                for (int i = 0; i < 4; ++i) O[ni][i] *= cr[i];
        }
        float sum = 0.f;
#pragma unroll
        for (int j = 0; j < 8; ++j) { p[j] = __expf(p[j] - m_run); sum += p[j]; }
        sum += __shfl_xor(sum, 16);
        sum += __shfl_xor(sum, 32);
        l_run += sum;
        bf16x8 pa;
#pragma unroll
        for (int j = 0; j < 8; ++j) pa[j] = (bf16)p[j];

        // ---- PV
        __builtin_amdgcn_s_setprio(1);
#pragma unroll
        for (int ni = 0; ni < 16; ++ni) {
            bf16x8 vb = *(const bf16x8*)&Vs[buf][(ni * 64 + lane) * 8];
            O[ni] = MFMA16(pa, vb, O[ni]);
        }
        __builtin_amdgcn_s_setprio(0);

        if (tt < NT - 1) {           // write-late into other buffer
#pragma unroll
            for (int j = 0; j < 4; ++j) {
                *(ushort8*)&Ks[buf ^ 1][(j * 256 + t) * 8] = kst[j];
                *(ushort8*)&Vs[buf ^ 1][(j * 256 + t) * 8] = vst[j];
            }
        }
        __syncthreads();
    }

    // ---- normalized partial output + stats
    float il = 1.f / l_run;          // valid for q=l16
    float li[4];
#pragma unroll
    for (int i = 0; i < 4; ++i) li[i] = __shfl(il, 4 * lg + i);
#pragma unroll
    for (int ni = 0; ni < 16; ++ni)
#pragma unroll
        for (int i = 0; i < 4; ++i) {
            int q = q0 + 4 * lg + i;
            int d = 16 * ni + l16;
            Ot[((size_t)split * 4096 + q) * 256 + d] = (bf16)(O[ni][i] * li[i]);
        }
    if (lane < 16) {
        statm[split * 4096 + q0 + l16] = m_run;
        statl[split * 4096 + q0 + l16] = l_run;
    }
}

// ---------------------------------------------------------------------------
// Kernel 3: merge 8 splits inline, then z = att @ Wo^T + bo, channel LN.
// BM=32 (grid 128); Wo pre-packed bf16. UNCHANGED.
// ---------------------------------------------------------------------------
__global__ __launch_bounds__(256) void k_proj_ln(
    const bf16* __restrict__ Ot, const float* __restrict__ statm,
    const float* __restrict__ statl, const bf16* __restrict__ Wob,
    const float* __restrict__ bo, const float* __restrict__ ln_w,
    const float* __restrict__ ln_b, bf16* __restrict__ zn)
{
    __shared__ bf16 As[32][264];     // merged attention rows (full 256 cols)
    __shared__ bf16 Bs[256][40];
    __shared__ float psum[4][32], psq[4][32];
    __shared__ float mean_l[32], inv_l[32];

    const int t = threadIdx.x, lane = t & 63, w = t >> 6;
    const int l16 = lane & 15, lg = lane >> 4;
    const int q0 = blockIdx.x * 32;
    const int nsplit = 8;

    for (int rr = 0; rr < 2; ++rr) {
        const int rloc = rr * 16 + (t >> 4);
        const int qg = q0 + rloc;
        const int d0 = (t & 15) * 16;
        float M = -1e30f;
        for (int s = 0; s < nsplit; ++s) M = fmaxf(M, statm[s * 4096 + qg]);
        float den = 0.f;
        float a[16] = {};
        for (int s = 0; s < nsplit; ++s) {
            float c = __expf(statm[s * 4096 + qg] - M) * statl[s * 4096 + qg];
            den += c;
            const bf16* pp = Ot + ((size_t)s * 4096 + qg) * 256 + d0;
            bf16x8 v0 = *(const bf16x8*)pp;
            bf16x8 v1 = *(const bf16x8*)(pp + 8);
#pragma unroll
            for (int j = 0; j < 8; ++j) { a[j] += c * (float)v0[j]; a[8 + j] += c * (float)v1[j]; }
        }
        float inv = 1.f / den;
        bf16x8 o0, o1;
#pragma unroll
        for (int j = 0; j < 8; ++j) { o0[j] = (bf16)(a[j] * inv); o1[j] = (bf16)(a[8 + j] * inv); }
        *(bf16x8*)&As[rloc][d0] = o0;
        *(bf16x8*)&As[rloc][d0 + 8] = o1;
    }

    f32x4 acc[2][4] = {};
    for (int kc = 0; kc < 256; kc += 32) {
        __syncthreads();
        for (int p = 0; p < 4; ++p) {
            int e = t + 256 * p;          // 0..1023
            int n = e >> 2, c0 = (e & 3) * 8;
            *(ushort8*)&Bs[n][c0] =
                *(const ushort8*)(Wob + (size_t)n * 256 + kc + c0);
        }
        __syncthreads();
        bf16x8 af[2];
        for (int mi = 0; mi < 2; ++mi)
            af[mi] = frag_from(&As[16 * mi + l16][kc + 4 * lg],
                               &As[16 * mi + l16][kc + 4 * lg + 16]);
        for (int ni = 0; ni < 4; ++ni) {
            int n = 64 * w + 16 * ni + l16;
            bf16x8 bfr = frag_from(&Bs[n][4 * lg], &Bs[n][4 * lg + 16]);
            acc[0][ni] = MFMA16(af[0], bfr, acc[0][ni]);
            acc[1][ni] = MFMA16(af[1], bfr, acc[1][ni]);
        }
    }

    float z[2][4][4];
    float rs[2][4] = {}, rq[2][4] = {};
    for (int ni = 0; ni < 4; ++ni) {
        int n = 64 * w + 16 * ni + l16;
        float b_ = bo[n];
        for (int mi = 0; mi < 2; ++mi)
            for (int i = 0; i < 4; ++i) {
                float v = acc[mi][ni][i] + b_;
                z[mi][ni][i] = v;
                rs[mi][i] += v;
                rq[mi][i] += v * v;
            }
    }
    for (int mi = 0; mi < 2; ++mi)
        for (int i = 0; i < 4; ++i) {
            float s = rs[mi][i], q = rq[mi][i];
            for (int msk = 1; msk <= 8; msk <<= 1) {
                s += __shfl_xor(s, msk);
                q += __shfl_xor(q, msk);
            }
            if (l16 == 0) {
                psum[w][16 * mi + 4 * lg + i] = s;
                psq[w][16 * mi + 4 * lg + i] = q;
            }
        }
    __syncthreads();
    if (t < 32) {
        float s = psum[0][t] + psum[1][t] + psum[2][t] + psum[3][t];
        float q = psq[0][t] + psq[1][t] + psq[2][t] + psq[3][t];
        float mean = s * (1.f / 256.f);
        float var = q * (1.f / 256.f) - mean * mean;
        mean_l[t] = mean;
        inv_l[t] = rsqrtf(var + 1e-6f);
    }
    __syncthreads();
    for (int ni = 0; ni < 4; ++ni) {
        int n = 64 * w + 16 * ni + l16;
        float g = ln_w[n], be = ln_b[n];
        for (int mi = 0; mi < 2; ++mi)
            for (int i = 0; i < 4; ++i) {
                int r = 16 * mi + 4 * lg + i;
                float v = (z[mi][ni][i] - mean_l[r]) * inv_l[r] * g + be;
                zn[(q0 + r) * 256 + n] = (bf16)v;
            }
    }
}

// ---------------------------------------------------------------------------
// Kernel 4: t1 = gelu(zn @ W1^T + b1). K-phases of 128: 4 barriers (was 16).
// ---------------------------------------------------------------------------
__global__ __launch_bounds__(256) void k_mlp1(
    const bf16* __restrict__ zn, const bf16* __restrict__ W1b,
    const float* __restrict__ b1, bf16* __restrict__ t1)
{
    __shared__ bf16 As[64][136];
    __shared__ bf16 Bs[64][136];
    __shared__ bf16 Tt[64][72];
    const int t = threadIdx.x, lane = t & 63, w = t >> 6;
    const int l16 = lane & 15, lg = lane >> 4;
    const int wr = w >> 1, wc = w & 1;
    const int i0 = blockIdx.x * 64, n0 = blockIdx.y * 64;
    f32x4 acc[2][2] = {};
    for (int ph = 0; ph < 2; ++ph) {
        const int kc0 = ph * 128;
        __syncthreads();
        for (int p = 0; p < 4; ++p) {
            int e = t + 256 * p;          // 0..1023
            int r = e >> 4, u = e & 15;
            *(ushort8*)&As[r][u * 8] =
                *(const ushort8*)(zn + (size_t)(i0 + r) * 256 + kc0 + u * 8);
        }
        for (int p = 0; p < 4; ++p) {
            int e = t + 256 * p;
            int n = e >> 4, c0 = (e & 15) * 8;
            *(ushort8*)&Bs[n][c0] =
                *(const ushort8*)(W1b + (size_t)(n0 + n) * 256 + kc0 + c0);
        }
        __syncthreads();
#pragma unroll
        for (int kc = 0; kc < 4; ++kc) {
            const int c0 = 32 * kc + 4 * lg;
            bf16x8 af[2], bfr[2];
            for (int mi = 0; mi < 2; ++mi) {
                int m = 32 * wr + 16 * mi + l16;
                af[mi] = frag_from(&As[m][c0], &As[m][c0 + 16]);
            }
            for (int ni = 0; ni < 2; ++ni) {
                int n = 32 * wc + 16 * ni + l16;
                bfr[ni] = frag_from(&Bs[n][c0], &Bs[n][c0 + 16]);
            }
            for (int mi = 0; mi < 2; ++mi)
                for (int ni = 0; ni < 2; ++ni)
                    acc[mi][ni] = MFMA16(af[mi], bfr[ni], acc[mi][ni]);
        }
    }
    for (int ni = 0; ni < 2; ++ni) {
        int n = 32 * wc + 16 * ni + l16;
        float b_ = b1[n0 + n];
        for (int mi = 0; mi < 2; ++mi)
            for (int i = 0; i < 4; ++i) {
                float h = acc[mi][ni][i] + b_;
                float g = 0.5f * h * (1.f + erff(h * 0.70710678118f));
                Tt[32 * wr + 16 * mi + 4 * lg + i][n] = (bf16)g;
            }
    }
    __syncthreads();
    for (int p = 0; p < 2; ++p) {
        int e = t + 256 * p;
        int r = e >> 3, u = e & 7;
        *(bf16x8*)(t1 + (i0 + r) * 512 + n0 + 8 * u) = *(bf16x8*)&Tt[r][8 * u];
    }
}

// ---------------------------------------------------------------------------
// Kernel 5: t = t1 @ W2^T + b2; out[c][i] = x[c][i] + t[i][c].
// K-phases of 128 over K=512: 8 barriers (was 32).
// ---------------------------------------------------------------------------
__global__ __launch_bounds__(256) void k_mlp2(
    const bf16* __restrict__ t1, const bf16* __restrict__ W2b,
    const float* __restrict__ b2, const float* __restrict__ x,
    float* __restrict__ out)
{
    __shared__ bf16 As[64][136];
    __shared__ bf16 Bs[64][136];
    __shared__ float T[64][65];
    const int t = threadIdx.x, lane = t & 63, w = t >> 6;
    const int l16 = lane & 15, lg = lane >> 4;
    const int wr = w >> 1, wc = w & 1;
    const int i0 = blockIdx.x * 64, n0 = blockIdx.y * 64;
    f32x4 acc[2][2] = {};
    for (int ph = 0; ph < 4; ++ph) {
        const int kc0 = ph * 128;
        __syncthreads();
        for (int p = 0; p < 4; ++p) {
            int e = t + 256 * p;          // 0..1023
            int r = e >> 4, u = e & 15;
            *(ushort8*)&As[r][u * 8] =
                *(const ushort8*)(t1 + (size_t)(i0 + r) * 512 + kc0 + u * 8);
        }
        for (int p = 0; p < 4; ++p) {
            int e = t + 256 * p;
            int n = e >> 4, c0 = (e & 15) * 8;
            *(ushort8*)&Bs[n][c0] =
                *(const ushort8*)(W2b + (size_t)(n0 + n) * 512 + kc0 + c0);
        }
        __syncthreads();
#pragma unroll
        for (int kc = 0; kc < 4; ++kc) {
            const int c0 = 32 * kc + 4 * lg;
            bf16x8 af[2], bfr[2];
            for (int mi = 0; mi < 2; ++mi) {
                int m = 32 * wr + 16 * mi + l16;
                af[mi] = frag_from(&As[m][c0], &As[m][c0 + 16]);
            }
            for (int ni = 0; ni < 2; ++ni) {
                int n = 32 * wc + 16 * ni + l16;
                bfr[ni] = frag_from(&Bs[n][c0], &Bs[n][c0 + 16]);
            }
            for (int mi = 0; mi < 2; ++mi)
                for (int ni = 0; ni < 2; ++ni)
                    acc[mi][ni] = MFMA16(af[mi], bfr[ni], acc[mi][ni]);
        }
    }
    for (int ni = 0; ni < 2; ++ni) {
        int nn = 32 * wc + 16 * ni + l16;
        float b_ = b2[n0 + nn];
        for (int mi = 0; mi < 2; ++mi)
            for (int i = 0; i < 4; ++i) {
                int mloc = 32 * wr + 16 * mi + 4 * lg + i;
                T[nn][mloc] = acc[mi][ni][i] + b_;
            }
    }
    __syncthreads();
    for (int p = 0; p < 4; ++p) {
        int e = t + 256 * p;              // 0..1023
        int nn = e >> 4, m4 = (e & 15) * 4;
        int c = n0 + nn, m = i0 + m4;
        f32x4 xv = *(const f32x4*)&x[c * 4096 + m];
        f32x4 o;
        for (int j = 0; j < 4; ++j) o[j] = xv[j] + T[nn][m4 + j];
        *(f32x4*)&out[c * 4096 + m] = o;
    }
}

// ---------------------------------------------------------------------------
extern "C" void kernel_launch(void* const* d_in, const int* in_sizes, int n_in,
                              void* d_out, int out_size, void* d_ws, size_t ws_size,
                              hipStream_t stream) {
    (void)in_sizes; (void)n_in; (void)out_size; (void)ws_size;
    const float* x   = (const float*)d_in[0];
    const float* y   = (const float*)d_in[1];
    const float* Wq  = (const float*)d_in[2];
    const float* bq  = (const float*)d_in[3];
    const float* Wk  = (const float*)d_in[4];
    const float* bk  = (const float*)d_in[5];
    const float* Wv  = (const float*)d_in[6];
    const float* bv  = (const float*)d_in[7];
    const float* Wo  = (const float*)d_in[8];
    const float* bo  = (const float*)d_in[9];
    const float* lnw = (const float*)d_in[10];
    const float* lnb = (const float*)d_in[11];
    const float* W1  = (const float*)d_in[12];
    const float* b1  = (const float*)d_in[13];
    const float* W2  = (const float*)d_in[14];
    const float* b2  = (const float*)d_in[15];
    float* out = (float*)d_out;

    char* ws = (char*)d_ws;
    const size_t MB = 1u << 20;
    const size_t KB = 1u << 10;
    // Layout (peak 23.5 MB):
    //  [0,2)      Qf    -> zn after flash
    //  [2,4)      Kf
    //  [4,6)      Vf
    //  [6,6.25)   statm (8 splits)   [6.25,6.5) statl
    //  [6.5,7.5)  packed bf16 weights (Wqb,Wkb,Wvb,Wob 128K; W1b,W2b 256K)
    //  [7.5,23.5) Ot (16MB); t1 reuses Ot post-proj_ln
    bf16*  Qf    = (bf16*)(ws + 0 * MB);
    bf16*  Kf    = (bf16*)(ws + 2 * MB);
    bf16*  Vf    = (bf16*)(ws + 4 * MB);
    float* statm = (float*)(ws + 6 * MB);
    float* statl = (float*)(ws + 6 * MB + 256 * KB);
    char*  wreg  = ws + 6 * MB + 512 * KB;
    bf16*  Wqb   = (bf16*)(wreg + 0 * KB);
    bf16*  Wkb   = (bf16*)(wreg + 128 * KB);
    bf16*  Wvb   = (bf16*)(wreg + 256 * KB);
    bf16*  Wob   = (bf16*)(wreg + 384 * KB);
    bf16*  W1b   = (bf16*)(wreg + 512 * KB);
    bf16*  W2b   = (bf16*)(wreg + 768 * KB);
    char*  big   = ws + 7 * MB + 512 * KB;
    bf16*  Ot    = (bf16*)big;
    bf16*  t1    = (bf16*)big;                 // post-proj_ln only (Ot dead)
    bf16*  zn    = (bf16*)(ws + 0 * MB);       // post-flash (Qf dead)

    k_wpack<<<dim3(256), 256, 0, stream>>>(Wq, Wk, Wv, Wo, W1, W2,
                                           Wqb, Wkb, Wvb, Wob, W1b, W2b);
    k_qkv<<<dim3(64, 4, 3), 256, 0, stream>>>(x, y, Wqb, bq, Wkb, bk, Wvb, bv,
                                              Qf, Kf, Vf);
    k_flash<<<dim3(64, 8), 256, 0, stream>>>(Qf, Kf, Vf, Ot, statm, statl);
    k_proj_ln<<<dim3(128), 256, 0, stream>>>(Ot, statm, statl, Wob, bo, lnw, lnb, zn);
    k_mlp1<<<dim3(64, 8), 256, 0, stream>>>(zn, W1b, b1, t1);
    k_mlp2<<<dim3(64, 4), 256, 0, stream>>>(t1, W2b, b2, x, out);
}

// Round 20
// 75.709 us; speedup vs baseline: 1.3751x; 1.0369x over previous
//
#include <hip/hip_runtime.h>
#include <hip/hip_bf16.h>
#include <math.h>

typedef __bf16 bf16;
typedef __bf16 bf16x4 __attribute__((ext_vector_type(4)));
typedef __bf16 bf16x8 __attribute__((ext_vector_type(8)));
typedef float f32x4 __attribute__((ext_vector_type(4)));
typedef unsigned short ushort8 __attribute__((ext_vector_type(8)));

#define MFMA16(a, b, c) __builtin_amdgcn_mfma_f32_16x16x32_bf16(a, b, c, 0, 0, 0)

__device__ inline bf16x8 frag2(bf16x4 a, bf16x4 b) {
    bf16x8 r;
    r[0] = a[0]; r[1] = a[1]; r[2] = a[2]; r[3] = a[3];
    r[4] = b[0]; r[5] = b[1]; r[6] = b[2]; r[7] = b[3];
    return r;
}

__device__ inline bf16x8 frag_from(const bf16* p0, const bf16* p1) {
    return frag2(*(const bf16x4*)p0, *(const bf16x4*)p1);
}

// ---------------------------------------------------------------------------
// Kernel W: pack all six fp32 weights to bf16 (one-time, ~0.5 MB total).
// ---------------------------------------------------------------------------
__global__ __launch_bounds__(256) void k_wpack(
    const float* __restrict__ Wq, const float* __restrict__ Wk,
    const float* __restrict__ Wv, const float* __restrict__ Wo,
    const float* __restrict__ W1, const float* __restrict__ W2,
    bf16* __restrict__ Wqb, bf16* __restrict__ Wkb, bf16* __restrict__ Wvb,
    bf16* __restrict__ Wob, bf16* __restrict__ W1b, bf16* __restrict__ W2b)
{
    const unsigned u = blockIdx.x * 256 + threadIdx.x;   // 0..65535
    const float* src; bf16* dst; unsigned off;
    if      (u < 8192)  { src = Wq; dst = Wqb; off = u; }
    else if (u < 16384) { src = Wk; dst = Wkb; off = u - 8192; }
    else if (u < 24576) { src = Wv; dst = Wvb; off = u - 16384; }
    else if (u < 32768) { src = Wo; dst = Wob; off = u - 24576; }
    else if (u < 49152) { src = W1; dst = W1b; off = u - 32768; }
    else                { src = W2; dst = W2b; off = u - 49152; }
    f32x4 a = *(const f32x4*)(src + (size_t)off * 8);
    f32x4 b = *(const f32x4*)(src + (size_t)off * 8 + 4);
    bf16x8 v;
#pragma unroll
    for (int j = 0; j < 4; ++j) { v[j] = (bf16)a[j]; v[4 + j] = (bf16)b[j]; }
    *(bf16x8*)(dst + (size_t)off * 8) = v;
}

// ---------------------------------------------------------------------------
// Kernel 1: QKV projections, frag-linear outputs. K-phases of 128.
// ---------------------------------------------------------------------------
__global__ __launch_bounds__(256) void k_qkv(
    const float* __restrict__ x, const float* __restrict__ y,
    const bf16* __restrict__ Wqb, const float* __restrict__ bq,
    const bf16* __restrict__ Wkb, const float* __restrict__ bk,
    const bf16* __restrict__ Wvb, const float* __restrict__ bv,
    bf16* __restrict__ Qf, bf16* __restrict__ Kf, bf16* __restrict__ Vf)
{
    const int zi = blockIdx.z;
    const float* src  = (zi == 0) ? x : y;
    const bf16* W     = (zi == 0) ? Wqb : (zi == 1 ? Wkb : Wvb);
    const float* bias = (zi == 0) ? bq : (zi == 1 ? bk : bv);
    bf16* dst         = (zi == 0) ? Qf : (zi == 1 ? Kf : Vf);
    const float scale = (zi == 0) ? 0.0625f : 1.0f;

    const int i0 = blockIdx.x * 64;
    const int o0 = blockIdx.y * 64;
    const int t = threadIdx.x;
    const int lane = t & 63;
    const int w = t >> 6;
    const int wr = w >> 1, wc = w & 1;
    const int l16 = lane & 15, lg = lane >> 4;

    __shared__ bf16 As[64][136];  // [m][k-phase 128]
    __shared__ bf16 Bs[64][136];  // [n][k-phase 128]
    __shared__ bf16 Tt[64][72];   // epilogue tile [row=pos][col=channel]

    f32x4 acc[2][2] = {};

    for (int ph = 0; ph < 2; ++ph) {
        const int kc0 = ph * 128;
        __syncthreads();
        for (int p = 0; p < 8; ++p) {
            int e = t + 256 * p;          // 0..2047
            int c = e >> 4, m0 = (e & 15) * 4;
            f32x4 v = *(const f32x4*)&src[(kc0 + c) * 4096 + i0 + m0];
            for (int j = 0; j < 4; ++j) As[m0 + j][c] = (bf16)v[j];
        }
        for (int p = 0; p < 4; ++p) {
            int e = t + 256 * p;          // 0..1023
            int n = e >> 4, c0 = (e & 15) * 8;
            *(ushort8*)&Bs[n][c0] =
                *(const ushort8*)(W + (size_t)(o0 + n) * 256 + kc0 + c0);
        }
        __syncthreads();
#pragma unroll
        for (int kc = 0; kc < 4; ++kc) {
            const int c0 = 32 * kc + 4 * lg;
            bf16x8 af[2], bfr[2];
            for (int mi = 0; mi < 2; ++mi) {
                int m = 32 * wr + 16 * mi + l16;
                af[mi] = frag_from(&As[m][c0], &As[m][c0 + 16]);
            }
            for (int ni = 0; ni < 2; ++ni) {
                int n = 32 * wc + 16 * ni + l16;
                bfr[ni] = frag_from(&Bs[n][c0], &Bs[n][c0 + 16]);
            }
            for (int mi = 0; mi < 2; ++mi)
                for (int ni = 0; ni < 2; ++ni)
                    acc[mi][ni] = MFMA16(af[mi], bfr[ni], acc[mi][ni]);
        }
    }

    for (int mi = 0; mi < 2; ++mi)
        for (int ni = 0; ni < 2; ++ni) {
            int n = 32 * wc + 16 * ni + l16;
            float bv_ = bias[o0 + n];
            for (int i = 0; i < 4; ++i)
                Tt[32 * wr + 16 * mi + 4 * lg + i][n] =
                    (bf16)((acc[mi][ni][i] + bv_) * scale);
        }
    __syncthreads();

    if (zi != 2) {
        // Q/K pack (frag-linear)
        for (int p = 0; p < 2; ++p) {
            int u = t + 256 * p;              // 0..511
            int Tl = u >> 8, cl = (u >> 7) & 1, kcl = (u >> 6) & 1, ln = u & 63;
            int l16_ = ln & 15, lg_ = ln >> 4;
            int r = 32 * Tl + 16 * cl + l16_;
            int c0 = 32 * kcl + 4 * lg_;
            bf16x8 v = frag_from(&Tt[r][c0], &Tt[r][c0 + 16]);
            size_t U = (size_t)(i0 / 32 + Tl) * 1024 + (size_t)cl * 512
                     + (size_t)(o0 / 32 + kcl) * 64 + ln;
            *(bf16x8*)(dst + U * 8) = v;
        }
    } else {
        // V pack (B-operand layout)
        for (int p = 0; p < 2; ++p) {
            int u = t + 256 * p;              // 0..511
            int Tl = u >> 8, nil = (u >> 6) & 3, ln = u & 63;
            int l16_ = ln & 15, lg_ = ln >> 4;
            bf16x8 v;
            for (int j = 0; j < 4; ++j) {
                v[j]     = Tt[32 * Tl + 4 * lg_ + j][16 * nil + l16_];
                v[4 + j] = Tt[32 * Tl + 16 + 4 * lg_ + j][16 * nil + l16_];
            }
            size_t U = (size_t)(i0 / 32 + Tl) * 1024
                     + (size_t)(o0 / 16 + nil) * 64 + ln;
            *(bf16x8*)(dst + U * 8) = v;
        }
    }
}

// ---------------------------------------------------------------------------
// Kernel 2: flash attention — R12 anchor (best measured). UNCHANGED.
// ---------------------------------------------------------------------------
__global__ __launch_bounds__(256) void k_flash(
    const bf16* __restrict__ Qf, const bf16* __restrict__ Kf,
    const bf16* __restrict__ Vf, bf16* __restrict__ Ot,
    float* __restrict__ statm, float* __restrict__ statl)
{
    __shared__ bf16 Ks[2][8192];    // 16KB per buf, frag-linear tile
    __shared__ bf16 Vs[2][8192];

    const int t = threadIdx.x;
    const int lane = t & 63;
    const int w = t >> 6;
    const int l16 = lane & 15, lg = lane >> 4;
    const int q0 = blockIdx.x * 64 + w * 16;   // wave's 16 q-rows
    const int split = blockIdx.y;              // 0..7
    const int T0 = split * 16;
    const int NT = 16;

    bf16x8 Qfr[8];
    {
        const bf16* qbp = Qf + ((size_t)(q0 >> 5) * 1024 + (size_t)((q0 >> 4) & 1) * 512) * 8;
#pragma unroll
        for (int kc = 0; kc < 8; ++kc)
            Qfr[kc] = *(const bf16x8*)(qbp + (kc * 64 + lane) * 8);
    }

    float m_run = -1e30f, l_run = 0.f;
    f32x4 O[16] = {};   // O[ni][i] = O[q0+4lg+i][16ni+l16]

    ushort8 kst[4], vst[4];
#pragma unroll
    for (int j = 0; j < 4; ++j) {
        kst[j] = *(const ushort8*)(Kf + ((size_t)T0 * 1024 + j * 256 + t) * 8);
        vst[j] = *(const ushort8*)(Vf + ((size_t)T0 * 1024 + j * 256 + t) * 8);
    }
#pragma unroll
    for (int j = 0; j < 4; ++j) {
        *(ushort8*)&Ks[0][(j * 256 + t) * 8] = kst[j];
        *(ushort8*)&Vs[0][(j * 256 + t) * 8] = vst[j];
    }
    __syncthreads();

    for (int tt = 0; tt < NT; ++tt) {
        const int buf = tt & 1;
        if (tt < NT - 1) {           // issue next tile's loads early
            int T = T0 + tt + 1;
#pragma unroll
            for (int j = 0; j < 4; ++j) {
                kst[j] = *(const ushort8*)(Kf + ((size_t)T * 1024 + j * 256 + t) * 8);
                vst[j] = *(const ushort8*)(Vf + ((size_t)T * 1024 + j * 256 + t) * 8);
            }
        }

        // ---- QK^T (swapped): key = 16c+4lg+i (in-tile), q = l16
        f32x4 S0 = {}, S1 = {};
        __builtin_amdgcn_s_setprio(1);
#pragma unroll
        for (int kc = 0; kc < 8; ++kc) {
            bf16x8 k0 = *(const bf16x8*)&Ks[buf][(kc * 64 + lane) * 8];
            bf16x8 k1 = *(const bf16x8*)&Ks[buf][(512 + kc * 64 + lane) * 8];
            S0 = MFMA16(k0, Qfr[kc], S0);
            S1 = MFMA16(k1, Qfr[kc], S1);
        }
        __builtin_amdgcn_s_setprio(0);

        // ---- in-register online softmax, defer-rescale (THR=8)
        float p[8];
#pragma unroll
        for (int i = 0; i < 4; ++i) { p[i] = S0[i]; p[4 + i] = S1[i]; }
        float mx = p[0];
#pragma unroll
        for (int j = 1; j < 8; ++j) mx = fmaxf(mx, p[j]);
        mx = fmaxf(mx, __shfl_xor(mx, 16));
        mx = fmaxf(mx, __shfl_xor(mx, 32));
        if (__any(mx > m_run + 8.f)) {
            float mn = fmaxf(m_run, mx);
            float corr = __expf(m_run - mn);
            m_run = mn;
            l_run *= corr;
            float cr[4];
#pragma unroll
            for (int i = 0; i < 4; ++i) cr[i] = __shfl(corr, 4 * lg + i);
#pragma unroll
            for (int ni = 0; ni < 16; ++ni)
#pragma unroll
                for (int i = 0; i < 4; ++i) O[ni][i] *= cr[i];
        }
        float sum = 0.f;
#pragma unroll
        for (int j = 0; j < 8; ++j) { p[j] = __expf(p[j] - m_run); sum += p[j]; }
        sum += __shfl_xor(sum, 16);
        sum += __shfl_xor(sum, 32);
        l_run += sum;
        bf16x8 pa;
#pragma unroll
        for (int j = 0; j < 8; ++j) pa[j] = (bf16)p[j];

        // ---- PV
        __builtin_amdgcn_s_setprio(1);
#pragma unroll
        for (int ni = 0; ni < 16; ++ni) {
            bf16x8 vb = *(const bf16x8*)&Vs[buf][(ni * 64 + lane) * 8];
            O[ni] = MFMA16(pa, vb, O[ni]);
        }
        __builtin_amdgcn_s_setprio(0);

        if (tt < NT - 1) {           // write-late into other buffer
#pragma unroll
            for (int j = 0; j < 4; ++j) {
                *(ushort8*)&Ks[buf ^ 1][(j * 256 + t) * 8] = kst[j];
                *(ushort8*)&Vs[buf ^ 1][(j * 256 + t) * 8] = vst[j];
            }
        }
        __syncthreads();
    }

    // ---- normalized partial output + stats
    float il = 1.f / l_run;          // valid for q=l16
    float li[4];
#pragma unroll
    for (int i = 0; i < 4; ++i) li[i] = __shfl(il, 4 * lg + i);
#pragma unroll
    for (int ni = 0; ni < 16; ++ni)
#pragma unroll
        for (int i = 0; i < 4; ++i) {
            int q = q0 + 4 * lg + i;
            int d = 16 * ni + l16;
            Ot[((size_t)split * 4096 + q) * 256 + d] = (bf16)(O[ni][i] * li[i]);
        }
    if (lane < 16) {
        statm[split * 4096 + q0 + l16] = m_run;
        statl[split * 4096 + q0 + l16] = l_run;
    }
}

// ---------------------------------------------------------------------------
// Kernel 3: merge 8 splits inline, then z = att @ Wo^T + bo, channel LN.
// BM=16, grid 256 (full GPU); K-phases of 64 -> 8 barriers (was 16).
// ---------------------------------------------------------------------------
__global__ __launch_bounds__(256) void k_proj_ln(
    const bf16* __restrict__ Ot, const float* __restrict__ statm,
    const float* __restrict__ statl, const bf16* __restrict__ Wob,
    const float* __restrict__ bo, const float* __restrict__ ln_w,
    const float* __restrict__ ln_b, bf16* __restrict__ zn)
{
    __shared__ bf16 As[16][264];     // merged attention rows (full 256 cols)
    __shared__ bf16 Bs[256][72];     // Wo K-phase (64 cols)
    __shared__ float psum[4][16], psq[4][16];
    __shared__ float mean_l[16], inv_l[16];

    const int t = threadIdx.x, lane = t & 63, w = t >> 6;
    const int l16 = lane & 15, lg = lane >> 4;
    const int q0 = blockIdx.x * 16;
    const int nsplit = 8;

    // ---- merge splits: thread t -> q = t>>4, d-chunk = (t&15)*16
    {
        const int qg = q0 + (t >> 4);
        const int d0 = (t & 15) * 16;
        float M = -1e30f;
        for (int s = 0; s < nsplit; ++s) M = fmaxf(M, statm[s * 4096 + qg]);
        float den = 0.f;
        float a[16] = {};
        for (int s = 0; s < nsplit; ++s) {
            float c = __expf(statm[s * 4096 + qg] - M) * statl[s * 4096 + qg];
            den += c;
            const bf16* pp = Ot + ((size_t)s * 4096 + qg) * 256 + d0;
            bf16x8 v0 = *(const bf16x8*)pp;
            bf16x8 v1 = *(const bf16x8*)(pp + 8);
#pragma unroll
            for (int j = 0; j < 8; ++j) { a[j] += c * (float)v0[j]; a[8 + j] += c * (float)v1[j]; }
        }
        float inv = 1.f / den;
        bf16x8 o0, o1;
#pragma unroll
        for (int j = 0; j < 8; ++j) { o0[j] = (bf16)(a[j] * inv); o1[j] = (bf16)(a[8 + j] * inv); }
        *(bf16x8*)&As[t >> 4][d0] = o0;
        *(bf16x8*)&As[t >> 4][d0 + 8] = o1;
    }

    f32x4 acc[4] = {};
    for (int ph = 0; ph < 4; ++ph) {
        const int kc0 = ph * 64;
        __syncthreads();
        for (int p = 0; p < 8; ++p) {
            int e = t + 256 * p;          // 0..2047
            int n = e >> 3, c0 = (e & 7) * 8;
            *(ushort8*)&Bs[n][c0] =
                *(const ushort8*)(Wob + (size_t)n * 256 + kc0 + c0);
        }
        __syncthreads();
#pragma unroll
        for (int kci = 0; kci < 2; ++kci) {
            const int cb = 32 * kci + 4 * lg;
            bf16x8 af = frag_from(&As[l16][kc0 + cb], &As[l16][kc0 + cb + 16]);
            for (int ni = 0; ni < 4; ++ni) {
                int n = 64 * w + 16 * ni + l16;
                bf16x8 bfr = frag_from(&Bs[n][cb], &Bs[n][cb + 16]);
                acc[ni] = MFMA16(af, bfr, acc[ni]);
            }
        }
    }

    float z[4][4];
    float rs[4] = {}, rq[4] = {};
    for (int ni = 0; ni < 4; ++ni) {
        int n = 64 * w + 16 * ni + l16;
        float b_ = bo[n];
        for (int i = 0; i < 4; ++i) {
            float v = acc[ni][i] + b_;
            z[ni][i] = v;
            rs[i] += v;
            rq[i] += v * v;
        }
    }
    for (int i = 0; i < 4; ++i) {
        float s = rs[i], q = rq[i];
        for (int msk = 1; msk <= 8; msk <<= 1) {
            s += __shfl_xor(s, msk);
            q += __shfl_xor(q, msk);
        }
        if (l16 == 0) { psum[w][4 * lg + i] = s; psq[w][4 * lg + i] = q; }
    }
    __syncthreads();
    if (t < 16) {
        float s = psum[0][t] + psum[1][t] + psum[2][t] + psum[3][t];
        float q = psq[0][t] + psq[1][t] + psq[2][t] + psq[3][t];
        float mean = s * (1.f / 256.f);
        float var = q * (1.f / 256.f) - mean * mean;
        mean_l[t] = mean;
        inv_l[t] = rsqrtf(var + 1e-6f);
    }
    __syncthreads();
    for (int ni = 0; ni < 4; ++ni) {
        int n = 64 * w + 16 * ni + l16;
        float g = ln_w[n], be = ln_b[n];
        for (int i = 0; i < 4; ++i) {
            int r = 4 * lg + i;
            float v = (z[ni][i] - mean_l[r]) * inv_l[r] * g + be;
            zn[(q0 + r) * 256 + n] = (bf16)v;
        }
    }
}

// ---------------------------------------------------------------------------
// Kernel 4: t1 = gelu(zn @ W1^T + b1). K-phases of 128: 4 barriers.
// ---------------------------------------------------------------------------
__global__ __launch_bounds__(256) void k_mlp1(
    const bf16* __restrict__ zn, const bf16* __restrict__ W1b,
    const float* __restrict__ b1, bf16* __restrict__ t1)
{
    __shared__ bf16 As[64][136];
    __shared__ bf16 Bs[64][136];
    __shared__ bf16 Tt[64][72];
    const int t = threadIdx.x, lane = t & 63, w = t >> 6;
    const int l16 = lane & 15, lg = lane >> 4;
    const int wr = w >> 1, wc = w & 1;
    const int i0 = blockIdx.x * 64, n0 = blockIdx.y * 64;
    f32x4 acc[2][2] = {};
    for (int ph = 0; ph < 2; ++ph) {
        const int kc0 = ph * 128;
        __syncthreads();
        for (int p = 0; p < 4; ++p) {
            int e = t + 256 * p;          // 0..1023
            int r = e >> 4, u = e & 15;
            *(ushort8*)&As[r][u * 8] =
                *(const ushort8*)(zn + (size_t)(i0 + r) * 256 + kc0 + u * 8);
        }
        for (int p = 0; p < 4; ++p) {
            int e = t + 256 * p;
            int n = e >> 4, c0 = (e & 15) * 8;
            *(ushort8*)&Bs[n][c0] =
                *(const ushort8*)(W1b + (size_t)(n0 + n) * 256 + kc0 + c0);
        }
        __syncthreads();
#pragma unroll
        for (int kc = 0; kc < 4; ++kc) {
            const int c0 = 32 * kc + 4 * lg;
            bf16x8 af[2], bfr[2];
            for (int mi = 0; mi < 2; ++mi) {
                int m = 32 * wr + 16 * mi + l16;
                af[mi] = frag_from(&As[m][c0], &As[m][c0 + 16]);
            }
            for (int ni = 0; ni < 2; ++ni) {
                int n = 32 * wc + 16 * ni + l16;
                bfr[ni] = frag_from(&Bs[n][c0], &Bs[n][c0 + 16]);
            }
            for (int mi = 0; mi < 2; ++mi)
                for (int ni = 0; ni < 2; ++ni)
                    acc[mi][ni] = MFMA16(af[mi], bfr[ni], acc[mi][ni]);
        }
    }
    for (int ni = 0; ni < 2; ++ni) {
        int n = 32 * wc + 16 * ni + l16;
        float b_ = b1[n0 + n];
        for (int mi = 0; mi < 2; ++mi)
            for (int i = 0; i < 4; ++i) {
                float h = acc[mi][ni][i] + b_;
                float g = 0.5f * h * (1.f + erff(h * 0.70710678118f));
                Tt[32 * wr + 16 * mi + 4 * lg + i][n] = (bf16)g;
            }
    }
    __syncthreads();
    for (int p = 0; p < 2; ++p) {
        int e = t + 256 * p;
        int r = e >> 3, u = e & 7;
        *(bf16x8*)(t1 + (i0 + r) * 512 + n0 + 8 * u) = *(bf16x8*)&Tt[r][8 * u];
    }
}

// ---------------------------------------------------------------------------
// Kernel 5: t = t1 @ W2^T + b2; out[c][i] = x[c][i] + t[i][c].
// K-phases of 128 over K=512: 8 barriers.
// ---------------------------------------------------------------------------
__global__ __launch_bounds__(256) void k_mlp2(
    const bf16* __restrict__ t1, const bf16* __restrict__ W2b,
    const float* __restrict__ b2, const float* __restrict__ x,
    float* __restrict__ out)
{
    __shared__ bf16 As[64][136];
    __shared__ bf16 Bs[64][136];
    __shared__ float T[64][65];
    const int t = threadIdx.x, lane = t & 63, w = t >> 6;
    const int l16 = lane & 15, lg = lane >> 4;
    const int wr = w >> 1, wc = w & 1;
    const int i0 = blockIdx.x * 64, n0 = blockIdx.y * 64;
    f32x4 acc[2][2] = {};
    for (int ph = 0; ph < 4; ++ph) {
        const int kc0 = ph * 128;
        __syncthreads();
        for (int p = 0; p < 4; ++p) {
            int e = t + 256 * p;          // 0..1023
            int r = e >> 4, u = e & 15;
            *(ushort8*)&As[r][u * 8] =
                *(const ushort8*)(t1 + (size_t)(i0 + r) * 512 + kc0 + u * 8);
        }
        for (int p = 0; p < 4; ++p) {
            int e = t + 256 * p;
            int n = e >> 4, c0 = (e & 15) * 8;
            *(ushort8*)&Bs[n][c0] =
                *(const ushort8*)(W2b + (size_t)(n0 + n) * 512 + kc0 + c0);
        }
        __syncthreads();
#pragma unroll
        for (int kc = 0; kc < 4; ++kc) {
            const int c0 = 32 * kc + 4 * lg;
            bf16x8 af[2], bfr[2];
            for (int mi = 0; mi < 2; ++mi) {
                int m = 32 * wr + 16 * mi + l16;
                af[mi] = frag_from(&As[m][c0], &As[m][c0 + 16]);
            }
            for (int ni = 0; ni < 2; ++ni) {
                int n = 32 * wc + 16 * ni + l16;
                bfr[ni] = frag_from(&Bs[n][c0], &Bs[n][c0 + 16]);
            }
            for (int mi = 0; mi < 2; ++mi)
                for (int ni = 0; ni < 2; ++ni)
                    acc[mi][ni] = MFMA16(af[mi], bfr[ni], acc[mi][ni]);
        }
    }
    for (int ni = 0; ni < 2; ++ni) {
        int nn = 32 * wc + 16 * ni + l16;
        float b_ = b2[n0 + nn];
        for (int mi = 0; mi < 2; ++mi)
            for (int i = 0; i < 4; ++i) {
                int mloc = 32 * wr + 16 * mi + 4 * lg + i;
                T[nn][mloc] = acc[mi][ni][i] + b_;
            }
    }
    __syncthreads();
    for (int p = 0; p < 4; ++p) {
        int e = t + 256 * p;              // 0..1023
        int nn = e >> 4, m4 = (e & 15) * 4;
        int c = n0 + nn, m = i0 + m4;
        f32x4 xv = *(const f32x4*)&x[c * 4096 + m];
        f32x4 o;
        for (int j = 0; j < 4; ++j) o[j] = xv[j] + T[nn][m4 + j];
        *(f32x4*)&out[c * 4096 + m] = o;
    }
}

// ---------------------------------------------------------------------------
extern "C" void kernel_launch(void* const* d_in, const int* in_sizes, int n_in,
                              void* d_out, int out_size, void* d_ws, size_t ws_size,
                              hipStream_t stream) {
    (void)in_sizes; (void)n_in; (void)out_size; (void)ws_size;
    const float* x   = (const float*)d_in[0];
    const float* y   = (const float*)d_in[1];
    const float* Wq  = (const float*)d_in[2];
    const float* bq  = (const float*)d_in[3];
    const float* Wk  = (const float*)d_in[4];
    const float* bk  = (const float*)d_in[5];
    const float* Wv  = (const float*)d_in[6];
    const float* bv  = (const float*)d_in[7];
    const float* Wo  = (const float*)d_in[8];
    const float* bo  = (const float*)d_in[9];
    const float* lnw = (const float*)d_in[10];
    const float* lnb = (const float*)d_in[11];
    const float* W1  = (const float*)d_in[12];
    const float* b1  = (const float*)d_in[13];
    const float* W2  = (const float*)d_in[14];
    const float* b2  = (const float*)d_in[15];
    float* out = (float*)d_out;

    char* ws = (char*)d_ws;
    const size_t MB = 1u << 20;
    const size_t KB = 1u << 10;
    // Layout (peak 23.5 MB):
    //  [0,2)      Qf    -> zn after flash
    //  [2,4)      Kf
    //  [4,6)      Vf
    //  [6,6.25)   statm (8 splits)   [6.25,6.5) statl
    //  [6.5,7.5)  packed bf16 weights (Wqb,Wkb,Wvb,Wob 128K; W1b,W2b 256K)
    //  [7.5,23.5) Ot (16MB); t1 reuses Ot post-proj_ln
    bf16*  Qf    = (bf16*)(ws + 0 * MB);
    bf16*  Kf    = (bf16*)(ws + 2 * MB);
    bf16*  Vf    = (bf16*)(ws + 4 * MB);
    float* statm = (float*)(ws + 6 * MB);
    float* statl = (float*)(ws + 6 * MB + 256 * KB);
    char*  wreg  = ws + 6 * MB + 512 * KB;
    bf16*  Wqb   = (bf16*)(wreg + 0 * KB);
    bf16*  Wkb   = (bf16*)(wreg + 128 * KB);
    bf16*  Wvb   = (bf16*)(wreg + 256 * KB);
    bf16*  Wob   = (bf16*)(wreg + 384 * KB);
    bf16*  W1b   = (bf16*)(wreg + 512 * KB);
    bf16*  W2b   = (bf16*)(wreg + 768 * KB);
    char*  big   = ws + 7 * MB + 512 * KB;
    bf16*  Ot    = (bf16*)big;
    bf16*  t1    = (bf16*)big;                 // post-proj_ln only (Ot dead)
    bf16*  zn    = (bf16*)(ws + 0 * MB);       // post-flash (Qf dead)

    k_wpack<<<dim3(256), 256, 0, stream>>>(Wq, Wk, Wv, Wo, W1, W2,
                                           Wqb, Wkb, Wvb, Wob, W1b, W2b);
    k_qkv<<<dim3(64, 4, 3), 256, 0, stream>>>(x, y, Wqb, bq, Wkb, bk, Wvb, bv,
                                              Qf, Kf, Vf);
    k_flash<<<dim3(64, 8), 256, 0, stream>>>(Qf, Kf, Vf, Ot, statm, statl);
    k_proj_ln<<<dim3(256), 256, 0, stream>>>(Ot, statm, statl, Wob, bo, lnw, lnb, zn);
    k_mlp1<<<dim3(64, 8), 256, 0, stream>>>(zn, W1b, b1, t1);
    k_mlp2<<<dim3(64, 4), 256, 0, stream>>>(t1, W2b, b2, x, out);
}